// Round 11
// baseline (8437.376 us; speedup 1.0000x reference)
//
#include <hip/hip_runtime.h>
#include <math.h>

#define NPAIR 131072          // 8192 freqs x 16 channels
#define STEPS 19
#define VMD_BLOCKS 256
#define N_GRP 16              // 16 groups x 16 blocks

// XOR swizzle: spreads strided radix-8 writes across banks; keeps contiguous free
#define SW(a) ((a) ^ (((a) >> 5) & 31))

__device__ __forceinline__ float2 cadd(float2 a, float2 b){ return make_float2(a.x+b.x, a.y+b.y); }
__device__ __forceinline__ float2 csub(float2 a, float2 b){ return make_float2(a.x-b.x, a.y-b.y); }
__device__ __forceinline__ float2 cmul(float2 a, float2 b){
    return make_float2(a.x*b.x - a.y*b.y, a.x*b.y + a.y*b.x);
}
template<int SGN>
__device__ __forceinline__ float2 imul(float2 a){   // multiply by e^{SGN*i*pi/2}
    return (SGN > 0) ? make_float2(-a.y, a.x) : make_float2(a.y, -a.x);
}

// 8-point DFT: y_k = sum_r a_r e^{SGN*2pi i r k/8}
template<int SGN>
__device__ __forceinline__ void dft8(const float2* a, float2* y){
    const float C = 0.70710678118654752f;
    const float sg = (SGN > 0) ? 1.f : -1.f;
    float2 t0 = cadd(a[0], a[4]), t1 = csub(a[0], a[4]);
    float2 t2 = cadd(a[2], a[6]), t3 = imul<SGN>(csub(a[2], a[6]));
    float2 E0 = cadd(t0, t2), E2 = csub(t0, t2), E1 = cadd(t1, t3), E3 = csub(t1, t3);
    float2 s0 = cadd(a[1], a[5]), s1 = csub(a[1], a[5]);
    float2 s2 = cadd(a[3], a[7]), s3 = imul<SGN>(csub(a[3], a[7]));
    float2 O0 = cadd(s0, s2), O2 = csub(s0, s2), O1 = cadd(s1, s3), O3 = csub(s1, s3);
    float2 w1 = make_float2(C, sg * C), w3 = make_float2(-C, sg * C);
    float2 R0 = O0, R1 = cmul(O1, w1), R2 = imul<SGN>(O2), R3 = cmul(O3, w3);
    y[0] = cadd(E0, R0); y[4] = csub(E0, R0);
    y[1] = cadd(E1, R1); y[5] = csub(E1, R1);
    y[2] = cadd(E2, R2); y[6] = csub(E2, R2);
    y[3] = cadd(E3, R3); y[7] = csub(E3, R3);
}

// ===== in-LDS 8192-pt Stockham FFT: 4 radix-8 passes + 1 radix-2, 1024 threads =====
template<int SGN>
__device__ void lds_fft8192_r8(float2* lds, int tid){
    #pragma unroll
    for (int pi = 0; pi < 4; pi++){
        int ls = 3 * pi;
        int s  = 1 << ls;
        int nn = 8192 >> ls;
        int q = tid & (s - 1);
        int p = tid >> ls;
        float2 a[8], y[8];
        #pragma unroll
        for (int r = 0; r < 8; r++) a[r] = lds[SW(tid + (r << 10))];
        __syncthreads();
        dft8<SGN>(a, y);
        float ang = (float)(2 * p) / (float)nn;
        float sn, cs;
        sincospif(SGN > 0 ? ang : -ang, &sn, &cs);   // w = e^{SGN*2pi i p/nn}
        float2 w = make_float2(cs, sn);
        float2 wk = make_float2(1.f, 0.f);
        int o = q + ((tid - q) << 3);                 // q + 8*s*p
        lds[SW(o)] = y[0];
        #pragma unroll
        for (int k = 1; k < 8; k++){
            wk = cmul(wk, w);
            lds[SW(o + (k << ls))] = cmul(y[k], wk);
        }
        __syncthreads();
    }
    #pragma unroll
    for (int w4 = 0; w4 < 4; w4++){                   // final radix-2, twiddle-free
        int idx = (w4 << 10) + tid;
        float2 a = lds[SW(idx)], b = lds[SW(idx + 4096)];
        lds[SW(idx)]        = cadd(a, b);
        lds[SW(idx + 4096)] = csub(a, b);
    }
    __syncthreads();
}

// ===== stage A: mirror-extend + FFT16384 (split radix via 2x FFT8192) -> FPT =====
__global__ __launch_bounds__(1024) void k_stageA(const float* __restrict__ sig,
                                                 float2* __restrict__ FPT){
    extern __shared__ float2 lds[];
    int tid = threadIdx.x;
    int cw  = blockIdx.x;
    int cs  = (cw + 8) & 15;                 // fftshift over channel axis
    const float* sp = sig + cs * 8192;
    float2 regA[8];
    #pragma unroll
    for (int r = 0; r < 8; r++){             // even samples of mirrored extension
        int p = r * 1024 + tid;
        int x = 2 * p;
        int mx = (x < 4096) ? (4095 - x) : ((x < 12288) ? (x - 4096) : (20479 - x));
        lds[SW(p)] = make_float2(sp[mx], 0.f);
    }
    __syncthreads();
    lds_fft8192_r8<-1>(lds, tid);
    #pragma unroll
    for (int r = 0; r < 8; r++) regA[r] = lds[SW(r * 1024 + tid)];
    __syncthreads();
    #pragma unroll
    for (int r = 0; r < 8; r++){             // odd samples
        int p = r * 1024 + tid;
        int x = 2 * p + 1;
        int mx = (x < 4096) ? (4095 - x) : ((x < 12288) ? (x - 4096) : (20479 - x));
        lds[SW(p)] = make_float2(sp[mx], 0.f);
    }
    __syncthreads();
    lds_fft8192_r8<-1>(lds, tid);
    // combine: F[j] = A[j] + e^{-i pi j/8192} B[j], j = q*1024+tid
    float sn, cn;
    sincospif(-(float)tid / 8192.0f, &sn, &cn);
    float2 w = make_float2(cn, sn);
    const float2 Wst = make_float2(0.92387953251128674f, -0.38268343236508977f); // e^{-i pi/8}
    #pragma unroll
    for (int q = 0; q < 8; q++){
        int j = q * 1024 + tid;
        float2 B = lds[SW(j)];
        float2 t = cmul(B, w);
        FPT[cw * 8192 + j] = make_float2(regA[q].x + t.x, regA[q].y + t.y);
        w = cmul(w, Wst);
    }
}

// ===== fused 19-step VMD: 2-level reduce + single omega computation + replicated broadcast ====
// Workspace doubles D:
//   NDH = D[0..304)      omega-history numer/denom totals (19 x 16)
//   BLK = D[304..4400)   per-block partials: 256 lines x 16 doubles
//   GRP = D[4400..4656)  per-group sums: 16 x 16 doubles
//   REL = D[4656..5168)  16 replicas x 32 doubles: [om[8] | flag(int) ...]
//   CNT = (int*)&D[5168] group counters (stride 32 ints, grp 0..15) + root at [512]
//   (zeroed region must reach D[5425) = CNT int 513 — R10 hang was exactly this)
__global__ __launch_bounds__(512, 2) void k_vmd_all(const float2* __restrict__ FPT,
                                                    float2* __restrict__ U,
                                                    double* __restrict__ D){
    double* NDH = D;
    double* BLK = D + 304;
    double* GRP = D + 4400;
    double* REL = D + 4656;
    int*    CNT = (int*)(D + 5168);

    int tid = blockIdx.x * 512 + threadIdx.x;   // [0,NPAIR), tid = cw*8192+j
    int j = tid & 8191;
    double fr = (double)j / 16384.0;
    float2 fv = FPT[tid];
    double fx = fv.x, fy = fv.y;
    float urx[8], ury[8];
    double om[8];
    #pragma unroll
    for (int k = 0; k < 8; k++){ urx[k] = 0.f; ury[k] = 0.f; om[k] = 0.0625 * (double)k; }
    __shared__ double lred[8][16];
    __shared__ double om_s[8];
    int lane = threadIdx.x & 63, wv = threadIdx.x >> 6;
    int grp = blockIdx.x >> 4;                  // 16 groups of 16 blocks

    for (int step = 0; step < STEPS; step++){
        if (step > 0){
            #pragma unroll
            for (int k = 0; k < 8; k++) om[k] = om_s[k];
        }
        double sx = 0.0, sy = 0.0;
        #pragma unroll
        for (int k = 1; k < 8; k++){ sx += (double)urx[k]; sy += (double)ury[k]; }
        double lx = 0.0, ly = 0.0, nloc[8], dloc[8];
        #pragma unroll
        for (int k = 0; k < 8; k++){
            if (k > 0){ sx += lx - (double)urx[k]; sy += ly - (double)ury[k]; }
            double d = fr - om[k];
            double den = 1.0 + 2000.0 * d * d;
            double nx = (fx - sx) / den, ny = (fy - sy) / den;
            urx[k] = (float)nx; ury[k] = (float)ny;   // replicate complex64 carry
            lx = nx; ly = ny;
            double pw = nx * nx + ny * ny;
            nloc[k] = fr * pw; dloc[k] = pw;
        }
        #pragma unroll
        for (int k = 0; k < 8; k++){
            double a = nloc[k], b = dloc[k];
            for (int off = 32; off > 0; off >>= 1){
                a += __shfl_down(a, off);
                b += __shfl_down(b, off);
            }
            nloc[k] = a; dloc[k] = b;
        }
        if (lane == 0){
            #pragma unroll
            for (int k = 0; k < 8; k++){ lred[wv][k] = nloc[k]; lred[wv][8 + k] = dloc[k]; }
        }
        __syncthreads();
        if (threadIdx.x < 16){
            double ps = 0.0;
            #pragma unroll
            for (int w = 0; w < 8; w++) ps += lred[w][threadIdx.x];
            // contention-free per-block partial (own 128-B line), device-visible store
            __hip_atomic_store(&BLK[blockIdx.x * 16 + threadIdx.x], ps,
                               __ATOMIC_RELAXED, __HIP_MEMORY_SCOPE_AGENT);
        }
        __syncthreads();                      // drains vmcnt block-wide before arrival RMW
        if (threadIdx.x == 0){
            int target = 16 * (step + 1);     // monotonic counters: no reset race
            int old = __hip_atomic_fetch_add(&CNT[grp * 32], 1,
                                             __ATOMIC_ACQ_REL, __HIP_MEMORY_SCOPE_AGENT);
            if (old == target - 1){           // group-last: all 16 members' BLK stores visible
                double acc[16];
                #pragma unroll
                for (int i = 0; i < 16; i++) acc[i] = 0.0;
                for (int bb = 0; bb < 16; bb++){
                    const double* bp = BLK + (grp * 16 + bb) * 16;
                    #pragma unroll
                    for (int i = 0; i < 16; i++)
                        acc[i] += __hip_atomic_load(&bp[i], __ATOMIC_RELAXED, __HIP_MEMORY_SCOPE_AGENT);
                }
                #pragma unroll
                for (int i = 0; i < 16; i++)
                    __hip_atomic_store(&GRP[grp * 16 + i], acc[i],
                                       __ATOMIC_RELAXED, __HIP_MEMORY_SCOPE_AGENT);
                int rold = __hip_atomic_fetch_add(&CNT[512], 1,
                                                  __ATOMIC_ACQ_REL, __HIP_MEMORY_SCOPE_AGENT);
                if (rold == target - 1){      // root-last: all 16 GRP sums visible
                    double tot[16];
                    #pragma unroll
                    for (int i = 0; i < 16; i++) tot[i] = 0.0;
                    for (int g = 0; g < 16; g++){
                        #pragma unroll
                        for (int i = 0; i < 16; i++)
                            tot[i] += __hip_atomic_load(&GRP[g * 16 + i],
                                                        __ATOMIC_RELAXED, __HIP_MEMORY_SCOPE_AGENT);
                    }
                    #pragma unroll
                    for (int i = 0; i < 16; i++)
                        __hip_atomic_store(&NDH[step * 16 + i], tot[i],
                                           __ATOMIC_RELAXED, __HIP_MEMORY_SCOPE_AGENT);
                    if (step < STEPS - 1){
                        double om8[8];
                        #pragma unroll
                        for (int k = 0; k < 8; k++) om8[k] = tot[k] / tot[8 + k];
                        for (int rep = 0; rep < 16; rep++){
                            double* rl = REL + rep * 32;
                            #pragma unroll
                            for (int k = 0; k < 8; k++)
                                __hip_atomic_store(&rl[k], om8[k],
                                                   __ATOMIC_RELAXED, __HIP_MEMORY_SCOPE_AGENT);
                        }
                        for (int rep = 0; rep < 16; rep++)
                            __hip_atomic_store((int*)(REL + rep * 32 + 8), step + 1,
                                               __ATOMIC_RELEASE, __HIP_MEMORY_SCOPE_AGENT);
                    }
                }
            }
            if (step < STEPS - 1){
                const int* myfl = (const int*)(REL + grp * 32 + 8);
                while (__hip_atomic_load(myfl, __ATOMIC_ACQUIRE,
                                         __HIP_MEMORY_SCOPE_AGENT) <= step)
                    __builtin_amdgcn_s_sleep(1);
                const double* rl = REL + grp * 32;
                #pragma unroll
                for (int k = 0; k < 8; k++)
                    om_s[k] = __hip_atomic_load(&rl[k], __ATOMIC_RELAXED, __HIP_MEMORY_SCOPE_AGENT);
            }
        }
        __syncthreads();
    }
    #pragma unroll
    for (int k = 0; k < 8; k++) U[k * NPAIR + tid] = make_float2(urx[k], ury[k]);
}

// ===== stage C+D: hermitian iFFT16384 -> slice -> FFT8192; results into own U slice =====
// After: U32[b*16384 + t] = y[t];  U32[b*16384 + 8192 + t] = Re(Yf[(t+4096) mod 8192])
__global__ __launch_bounds__(1024) void k_stageCD(float2* __restrict__ U){
    extern __shared__ float2 lds[];
    int tid = threadIdx.x;
    int b = blockIdx.x;                      // b = k*16 + cw
    const float2* pos = U + b * 8192;
    float* slice = (float*)(U) + (size_t)b * 16384;
    const float inv = 1.0f / 16384.0f;
    float2 regA[8];
    #pragma unroll
    for (int r = 0; r < 8; r++){             // v_even[p] = v[2p] (hermitian map)
        int p = r * 1024 + tid;
        int m = 2 * p;
        int jj; bool cj;
        if (m == 0)          { jj = 0;         cj = true;  }
        else if (m <= 8191)  { jj = m;         cj = false; }
        else if (m == 8192)  { jj = 8191;      cj = true;  }
        else                 { jj = 16384 - m; cj = true;  }
        float2 pv = pos[jj];
        lds[SW(p)] = make_float2(pv.x, cj ? -pv.y : pv.y);
    }
    __syncthreads();
    lds_fft8192_r8<1>(lds, tid);
    #pragma unroll
    for (int r = 0; r < 8; r++) regA[r] = lds[SW(r * 1024 + tid)];
    __syncthreads();
    #pragma unroll
    for (int r = 0; r < 8; r++){             // v_odd[p] = v[2p+1]
        int p = r * 1024 + tid;
        int m = 2 * p + 1;
        int jj; bool cj;
        if (m <= 8191) { jj = m;         cj = false; }
        else           { jj = 16384 - m; cj = true;  }
        float2 pv = pos[jj];
        lds[SW(p)] = make_float2(pv.x, cj ? -pv.y : pv.y);
    }
    __syncthreads();
    lds_fft8192_r8<1>(lds, tid);
    // combine -> y[t], coalesced write into own slice (all pos reads done)
    float yreg[8];
    float sn, cn;
    sincospif((float)(4096 + tid) / 8192.0f, &sn, &cn);
    float2 w = make_float2(cn, sn);
    const float2 Wst = make_float2(0.92387953251128674f, 0.38268343236508977f);  // e^{+i pi/8}
    #pragma unroll
    for (int q = 0; q < 8; q++){
        int t = q * 1024 + tid;
        int r = (q + 4) & 7;                 // (t+4096) mod 8192 block
        float2 A = regA[r];
        float2 B = lds[SW(r * 1024 + tid)];
        float2 tw = cmul(B, w);
        float yv = (A.x + tw.x) * inv;
        yreg[q] = yv;
        slice[t] = yv;
        w = cmul(w, Wst);
    }
    __syncthreads();
    #pragma unroll
    for (int q = 0; q < 8; q++) lds[SW(q * 1024 + tid)] = make_float2(yreg[q], 0.f);
    __syncthreads();
    lds_fft8192_r8<-1>(lds, tid);            // forward FFT8192 of y
    #pragma unroll
    for (int q = 0; q < 8; q++){
        int t = q * 1024 + tid;
        float2 Y = lds[SW(((q + 4) & 7) * 1024 + tid)];
        slice[8192 + t] = Y.x;               // Re(Yf[(t+4096) mod 8192]), coalesced
    }
}

// ===== transpose 1: out0[(k*8192+t)*16 + ch] = y[k*16+cw][t], ch=(cw+8)&15 =====
__global__ __launch_bounds__(256) void k_out0T(const float* __restrict__ U32,
                                               float* __restrict__ out){
    __shared__ float tile[16][257];
    int tid = threadIdx.x;
    int k  = blockIdx.y;
    int t0 = blockIdx.x * 256;
    #pragma unroll
    for (int cw = 0; cw < 16; cw++)
        tile[cw][tid] = U32[((size_t)(k * 16 + cw)) * 16384 + t0 + tid];
    __syncthreads();
    #pragma unroll
    for (int i = 0; i < 16; i++){
        int flat = i * 256 + tid;            // flat = dt*16 + ch
        int dt = flat >> 4, ch = flat & 15;
        int cw = (ch + 8) & 15;
        out[(size_t)k * 131072 + t0 * 16 + flat] = tile[cw][dt];
    }
}

// ===== transpose 2: out1[1048576 + t*128 + b] = W2[b][t] =====
__global__ __launch_bounds__(256) void k_out1T(const float* __restrict__ U32,
                                               float* __restrict__ out){
    __shared__ float tile[128][65];
    int tid = threadIdx.x;
    int t0 = blockIdx.x * 64;
    #pragma unroll
    for (int i = 0; i < 32; i++){
        int flat = i * 256 + tid;
        int b = flat >> 6, dt = flat & 63;
        tile[b][dt] = U32[(size_t)b * 16384 + 8192 + t0 + dt];
    }
    __syncthreads();
    #pragma unroll
    for (int i = 0; i < 32; i++){
        int flat = i * 256 + tid;
        int dt = flat >> 7, b = flat & 127;
        out[1048576 + (size_t)(t0 + dt) * 128 + b] = tile[b][dt];
    }
}

// ===== omega history: out2 = Re(omega), 160 floats at 2097152 =====
__global__ void k_omega(const double* __restrict__ ndh, float* __restrict__ out){
    int t = threadIdx.x;
    if (t >= 160) return;
    int row = t >> 3, k = t & 7;
    double v = (row == 0) ? 0.0625 * (double)k
                          : ndh[(row - 1) * 16 + k] / ndh[(row - 1) * 16 + 8 + k];
    out[2097152 + t] = (float)v;
}

__global__ void k_zerond(double* __restrict__ q, int n){
    int i = blockIdx.x * blockDim.x + threadIdx.x;
    if (i < n) q[i] = 0.0;
}

extern "C" void kernel_launch(void* const* d_in, const int* in_sizes, int n_in,
                              void* d_out, int out_size, void* d_ws, size_t ws_size,
                              hipStream_t stream){
    const float* sig = (const float*)d_in[0];
    float* out = (float*)d_out;
    char* p = (char*)d_ws;
    // ws: U 8 MB | FPT 1 MB | D (NDH/BLK/GRP/REL/CNT) ~43 KB   (~9.05 MB total)
    float2* U   = (float2*)p;
    float2* FPT = (float2*)(p + (size_t)8 * 1024 * 1024);
    double* D   = (double*)(p + (size_t)9 * 1024 * 1024);

    // zero REL + ENTIRE CNT span: D[4656 .. 5440)  (R10 hang: only reached 5236,
    // leaving CNT[160..512] = 0xAA poison -> barrier deadlock)
    k_zerond<<<dim3(4), dim3(256), 0, stream>>>(D + 4656, 784);
    k_stageA<<<dim3(16), dim3(1024), 65536, stream>>>(sig, FPT);
    k_vmd_all<<<dim3(VMD_BLOCKS), dim3(512), 0, stream>>>(FPT, U, D);
    k_stageCD<<<dim3(128), dim3(1024), 65536, stream>>>(U);
    k_out0T<<<dim3(32, 8), dim3(256), 0, stream>>>((const float*)U, out);
    k_out1T<<<dim3(128), dim3(256), 0, stream>>>((const float*)U, out);
    k_omega<<<dim3(1), dim3(256), 0, stream>>>(D, out);
}

// Round 12
// 1055.952 us; speedup vs baseline: 7.9903x; 7.9903x over previous
//
#include <hip/hip_runtime.h>
#include <math.h>

#define NPAIR 131072          // 8192 freqs x 16 channels
#define STEPS 19
#define VMD_BLOCKS 256
#define N_GRP 16              // 16 groups x 16 blocks

// XOR swizzle: spreads strided radix-8 writes across banks; keeps contiguous free
#define SW(a) ((a) ^ (((a) >> 5) & 31))

__device__ __forceinline__ float2 cadd(float2 a, float2 b){ return make_float2(a.x+b.x, a.y+b.y); }
__device__ __forceinline__ float2 csub(float2 a, float2 b){ return make_float2(a.x-b.x, a.y-b.y); }
__device__ __forceinline__ float2 cmul(float2 a, float2 b){
    return make_float2(a.x*b.x - a.y*b.y, a.x*b.y + a.y*b.x);
}
template<int SGN>
__device__ __forceinline__ float2 imul(float2 a){   // multiply by e^{SGN*i*pi/2}
    return (SGN > 0) ? make_float2(-a.y, a.x) : make_float2(a.y, -a.x);
}

// 8-point DFT: y_k = sum_r a_r e^{SGN*2pi i r k/8}
template<int SGN>
__device__ __forceinline__ void dft8(const float2* a, float2* y){
    const float C = 0.70710678118654752f;
    const float sg = (SGN > 0) ? 1.f : -1.f;
    float2 t0 = cadd(a[0], a[4]), t1 = csub(a[0], a[4]);
    float2 t2 = cadd(a[2], a[6]), t3 = imul<SGN>(csub(a[2], a[6]));
    float2 E0 = cadd(t0, t2), E2 = csub(t0, t2), E1 = cadd(t1, t3), E3 = csub(t1, t3);
    float2 s0 = cadd(a[1], a[5]), s1 = csub(a[1], a[5]);
    float2 s2 = cadd(a[3], a[7]), s3 = imul<SGN>(csub(a[3], a[7]));
    float2 O0 = cadd(s0, s2), O2 = csub(s0, s2), O1 = cadd(s1, s3), O3 = csub(s1, s3);
    float2 w1 = make_float2(C, sg * C), w3 = make_float2(-C, sg * C);
    float2 R0 = O0, R1 = cmul(O1, w1), R2 = imul<SGN>(O2), R3 = cmul(O3, w3);
    y[0] = cadd(E0, R0); y[4] = csub(E0, R0);
    y[1] = cadd(E1, R1); y[5] = csub(E1, R1);
    y[2] = cadd(E2, R2); y[6] = csub(E2, R2);
    y[3] = cadd(E3, R3); y[7] = csub(E3, R3);
}

// ===== in-LDS 8192-pt Stockham FFT: 4 radix-8 passes + 1 radix-2, 1024 threads =====
template<int SGN>
__device__ void lds_fft8192_r8(float2* lds, int tid){
    #pragma unroll
    for (int pi = 0; pi < 4; pi++){
        int ls = 3 * pi;
        int s  = 1 << ls;
        int nn = 8192 >> ls;
        int q = tid & (s - 1);
        int p = tid >> ls;
        float2 a[8], y[8];
        #pragma unroll
        for (int r = 0; r < 8; r++) a[r] = lds[SW(tid + (r << 10))];
        __syncthreads();
        dft8<SGN>(a, y);
        float ang = (float)(2 * p) / (float)nn;
        float sn, cs;
        sincospif(SGN > 0 ? ang : -ang, &sn, &cs);   // w = e^{SGN*2pi i p/nn}
        float2 w = make_float2(cs, sn);
        float2 wk = make_float2(1.f, 0.f);
        int o = q + ((tid - q) << 3);                 // q + 8*s*p
        lds[SW(o)] = y[0];
        #pragma unroll
        for (int k = 1; k < 8; k++){
            wk = cmul(wk, w);
            lds[SW(o + (k << ls))] = cmul(y[k], wk);
        }
        __syncthreads();
    }
    #pragma unroll
    for (int w4 = 0; w4 < 4; w4++){                   // final radix-2, twiddle-free
        int idx = (w4 << 10) + tid;
        float2 a = lds[SW(idx)], b = lds[SW(idx + 4096)];
        lds[SW(idx)]        = cadd(a, b);
        lds[SW(idx + 4096)] = csub(a, b);
    }
    __syncthreads();
}

// ===== stage A: mirror-extend + FFT16384 (split radix via 2x FFT8192) -> FPT =====
__global__ __launch_bounds__(1024) void k_stageA(const float* __restrict__ sig,
                                                 float2* __restrict__ FPT){
    extern __shared__ float2 lds[];
    int tid = threadIdx.x;
    int cw  = blockIdx.x;
    int cs  = (cw + 8) & 15;                 // fftshift over channel axis
    const float* sp = sig + cs * 8192;
    float2 regA[8];
    #pragma unroll
    for (int r = 0; r < 8; r++){             // even samples of mirrored extension
        int p = r * 1024 + tid;
        int x = 2 * p;
        int mx = (x < 4096) ? (4095 - x) : ((x < 12288) ? (x - 4096) : (20479 - x));
        lds[SW(p)] = make_float2(sp[mx], 0.f);
    }
    __syncthreads();
    lds_fft8192_r8<-1>(lds, tid);
    #pragma unroll
    for (int r = 0; r < 8; r++) regA[r] = lds[SW(r * 1024 + tid)];
    __syncthreads();
    #pragma unroll
    for (int r = 0; r < 8; r++){             // odd samples
        int p = r * 1024 + tid;
        int x = 2 * p + 1;
        int mx = (x < 4096) ? (4095 - x) : ((x < 12288) ? (x - 4096) : (20479 - x));
        lds[SW(p)] = make_float2(sp[mx], 0.f);
    }
    __syncthreads();
    lds_fft8192_r8<-1>(lds, tid);
    // combine: F[j] = A[j] + e^{-i pi j/8192} B[j], j = q*1024+tid
    float sn, cn;
    sincospif(-(float)tid / 8192.0f, &sn, &cn);
    float2 w = make_float2(cn, sn);
    const float2 Wst = make_float2(0.92387953251128674f, -0.38268343236508977f); // e^{-i pi/8}
    #pragma unroll
    for (int q = 0; q < 8; q++){
        int j = q * 1024 + tid;
        float2 B = lds[SW(j)];
        float2 t = cmul(B, w);
        FPT[cw * 8192 + j] = make_float2(regA[q].x + t.x, regA[q].y + t.y);
        w = cmul(w, Wst);
    }
}

// ===== fused 19-step VMD: 2-level reduce + single omega computation + replicated broadcast ====
// Workspace doubles D:
//   NDH = D[0..304)      omega-history numer/denom totals (19 x 16)
//   BLK = D[304..4400)   per-block partials: 256 lines x 16 doubles
//   GRP = D[4400..4656)  per-group sums: 16 x 16 doubles
//   REL = D[4656..5168)  16 replicas x 32 doubles: [om[8] | flag(int) ...]
//   CNT = (int*)&D[5168] group counters (stride 32 ints, grp 0..15) + root at [512]
// POLL RULE (R11 lesson): poll RELAXED only; ONE acquire after exit. Per-iteration
// AGENT-acquire emits an L2-wide invalidate on gfx950 -> 240 pollers wipe every
// XCD's L2 continuously (R11: 8.5 ms, FETCH 52 MB).
__global__ __launch_bounds__(512, 2) void k_vmd_all(const float2* __restrict__ FPT,
                                                    float2* __restrict__ U,
                                                    double* __restrict__ D){
    double* NDH = D;
    double* BLK = D + 304;
    double* GRP = D + 4400;
    double* REL = D + 4656;
    int*    CNT = (int*)(D + 5168);

    int tid = blockIdx.x * 512 + threadIdx.x;   // [0,NPAIR), tid = cw*8192+j
    int j = tid & 8191;
    double fr = (double)j / 16384.0;
    float2 fv = FPT[tid];
    double fx = fv.x, fy = fv.y;
    float urx[8], ury[8];
    double om[8];
    #pragma unroll
    for (int k = 0; k < 8; k++){ urx[k] = 0.f; ury[k] = 0.f; om[k] = 0.0625 * (double)k; }
    __shared__ double lred[8][16];
    __shared__ double om_s[8];
    int lane = threadIdx.x & 63, wv = threadIdx.x >> 6;
    int grp = blockIdx.x >> 4;                  // 16 groups of 16 blocks

    for (int step = 0; step < STEPS; step++){
        if (step > 0){
            #pragma unroll
            for (int k = 0; k < 8; k++) om[k] = om_s[k];
        }
        double sx = 0.0, sy = 0.0;
        #pragma unroll
        for (int k = 1; k < 8; k++){ sx += (double)urx[k]; sy += (double)ury[k]; }
        double lx = 0.0, ly = 0.0, nloc[8], dloc[8];
        #pragma unroll
        for (int k = 0; k < 8; k++){
            if (k > 0){ sx += lx - (double)urx[k]; sy += ly - (double)ury[k]; }
            double d = fr - om[k];
            double den = 1.0 + 2000.0 * d * d;
            double nx = (fx - sx) / den, ny = (fy - sy) / den;
            urx[k] = (float)nx; ury[k] = (float)ny;   // replicate complex64 carry
            lx = nx; ly = ny;
            double pw = nx * nx + ny * ny;
            nloc[k] = fr * pw; dloc[k] = pw;
        }
        #pragma unroll
        for (int k = 0; k < 8; k++){
            double a = nloc[k], b = dloc[k];
            for (int off = 32; off > 0; off >>= 1){
                a += __shfl_down(a, off);
                b += __shfl_down(b, off);
            }
            nloc[k] = a; dloc[k] = b;
        }
        if (lane == 0){
            #pragma unroll
            for (int k = 0; k < 8; k++){ lred[wv][k] = nloc[k]; lred[wv][8 + k] = dloc[k]; }
        }
        __syncthreads();
        if (threadIdx.x < 16){
            double ps = 0.0;
            #pragma unroll
            for (int w = 0; w < 8; w++) ps += lred[w][threadIdx.x];
            // contention-free per-block partial (own 128-B line), device-visible store
            __hip_atomic_store(&BLK[blockIdx.x * 16 + threadIdx.x], ps,
                               __ATOMIC_RELAXED, __HIP_MEMORY_SCOPE_AGENT);
        }
        __syncthreads();                      // drains vmcnt block-wide before arrival RMW
        if (threadIdx.x == 0){
            int target = 16 * (step + 1);     // monotonic counters: no reset race
            int old = __hip_atomic_fetch_add(&CNT[grp * 32], 1,
                                             __ATOMIC_ACQ_REL, __HIP_MEMORY_SCOPE_AGENT);
            if (old == target - 1){           // group-last: all 16 members' BLK stores visible
                double acc[16];
                #pragma unroll
                for (int i = 0; i < 16; i++) acc[i] = 0.0;
                for (int bb = 0; bb < 16; bb++){
                    const double* bp = BLK + (grp * 16 + bb) * 16;
                    #pragma unroll
                    for (int i = 0; i < 16; i++)
                        acc[i] += __hip_atomic_load(&bp[i], __ATOMIC_RELAXED, __HIP_MEMORY_SCOPE_AGENT);
                }
                #pragma unroll
                for (int i = 0; i < 16; i++)
                    __hip_atomic_store(&GRP[grp * 16 + i], acc[i],
                                       __ATOMIC_RELAXED, __HIP_MEMORY_SCOPE_AGENT);
                int rold = __hip_atomic_fetch_add(&CNT[512], 1,
                                                  __ATOMIC_ACQ_REL, __HIP_MEMORY_SCOPE_AGENT);
                if (rold == target - 1){      // root-last: all 16 GRP sums visible
                    double tot[16];
                    #pragma unroll
                    for (int i = 0; i < 16; i++) tot[i] = 0.0;
                    for (int g = 0; g < 16; g++){
                        #pragma unroll
                        for (int i = 0; i < 16; i++)
                            tot[i] += __hip_atomic_load(&GRP[g * 16 + i],
                                                        __ATOMIC_RELAXED, __HIP_MEMORY_SCOPE_AGENT);
                    }
                    #pragma unroll
                    for (int i = 0; i < 16; i++)
                        __hip_atomic_store(&NDH[step * 16 + i], tot[i],
                                           __ATOMIC_RELAXED, __HIP_MEMORY_SCOPE_AGENT);
                    if (step < STEPS - 1){
                        double om8[8];
                        #pragma unroll
                        for (int k = 0; k < 8; k++) om8[k] = tot[k] / tot[8 + k];
                        for (int rep = 0; rep < 16; rep++){
                            double* rl = REL + rep * 32;
                            #pragma unroll
                            for (int k = 0; k < 8; k++)
                                __hip_atomic_store(&rl[k], om8[k],
                                                   __ATOMIC_RELAXED, __HIP_MEMORY_SCOPE_AGENT);
                        }
                        for (int rep = 0; rep < 16; rep++)
                            __hip_atomic_store((int*)(REL + rep * 32 + 8), step + 1,
                                               __ATOMIC_RELEASE, __HIP_MEMORY_SCOPE_AGENT);
                    }
                }
            }
            if (step < STEPS - 1){
                const int* myfl = (const int*)(REL + grp * 32 + 8);
                // RELAXED poll (no L2 invalidate per iteration!) ...
                while (__hip_atomic_load(myfl, __ATOMIC_RELAXED,
                                         __HIP_MEMORY_SCOPE_AGENT) <= step)
                    __builtin_amdgcn_s_sleep(2);
                // ... then ONE acquire to order the subsequent om reads
                (void)__hip_atomic_load(myfl, __ATOMIC_ACQUIRE, __HIP_MEMORY_SCOPE_AGENT);
                const double* rl = REL + grp * 32;
                #pragma unroll
                for (int k = 0; k < 8; k++)
                    om_s[k] = __hip_atomic_load(&rl[k], __ATOMIC_RELAXED, __HIP_MEMORY_SCOPE_AGENT);
            }
        }
        __syncthreads();
    }
    #pragma unroll
    for (int k = 0; k < 8; k++) U[k * NPAIR + tid] = make_float2(urx[k], ury[k]);
}

// ===== stage C+D: hermitian iFFT16384 -> slice -> FFT8192; results into own U slice =====
// After: U32[b*16384 + t] = y[t];  U32[b*16384 + 8192 + t] = Re(Yf[(t+4096) mod 8192])
__global__ __launch_bounds__(1024) void k_stageCD(float2* __restrict__ U){
    extern __shared__ float2 lds[];
    int tid = threadIdx.x;
    int b = blockIdx.x;                      // b = k*16 + cw
    const float2* pos = U + b * 8192;
    float* slice = (float*)(U) + (size_t)b * 16384;
    const float inv = 1.0f / 16384.0f;
    float2 regA[8];
    #pragma unroll
    for (int r = 0; r < 8; r++){             // v_even[p] = v[2p] (hermitian map)
        int p = r * 1024 + tid;
        int m = 2 * p;
        int jj; bool cj;
        if (m == 0)          { jj = 0;         cj = true;  }
        else if (m <= 8191)  { jj = m;         cj = false; }
        else if (m == 8192)  { jj = 8191;      cj = true;  }
        else                 { jj = 16384 - m; cj = true;  }
        float2 pv = pos[jj];
        lds[SW(p)] = make_float2(pv.x, cj ? -pv.y : pv.y);
    }
    __syncthreads();
    lds_fft8192_r8<1>(lds, tid);
    #pragma unroll
    for (int r = 0; r < 8; r++) regA[r] = lds[SW(r * 1024 + tid)];
    __syncthreads();
    #pragma unroll
    for (int r = 0; r < 8; r++){             // v_odd[p] = v[2p+1]
        int p = r * 1024 + tid;
        int m = 2 * p + 1;
        int jj; bool cj;
        if (m <= 8191) { jj = m;         cj = false; }
        else           { jj = 16384 - m; cj = true;  }
        float2 pv = pos[jj];
        lds[SW(p)] = make_float2(pv.x, cj ? -pv.y : pv.y);
    }
    __syncthreads();
    lds_fft8192_r8<1>(lds, tid);
    // combine -> y[t], coalesced write into own slice (all pos reads done)
    float yreg[8];
    float sn, cn;
    sincospif((float)(4096 + tid) / 8192.0f, &sn, &cn);
    float2 w = make_float2(cn, sn);
    const float2 Wst = make_float2(0.92387953251128674f, 0.38268343236508977f);  // e^{+i pi/8}
    #pragma unroll
    for (int q = 0; q < 8; q++){
        int t = q * 1024 + tid;
        int r = (q + 4) & 7;                 // (t+4096) mod 8192 block
        float2 A = regA[r];
        float2 B = lds[SW(r * 1024 + tid)];
        float2 tw = cmul(B, w);
        float yv = (A.x + tw.x) * inv;
        yreg[q] = yv;
        slice[t] = yv;
        w = cmul(w, Wst);
    }
    __syncthreads();
    #pragma unroll
    for (int q = 0; q < 8; q++) lds[SW(q * 1024 + tid)] = make_float2(yreg[q], 0.f);
    __syncthreads();
    lds_fft8192_r8<-1>(lds, tid);            // forward FFT8192 of y
    #pragma unroll
    for (int q = 0; q < 8; q++){
        int t = q * 1024 + tid;
        float2 Y = lds[SW(((q + 4) & 7) * 1024 + tid)];
        slice[8192 + t] = Y.x;               // Re(Yf[(t+4096) mod 8192]), coalesced
    }
}

// ===== transpose 1: out0[(k*8192+t)*16 + ch] = y[k*16+cw][t], ch=(cw+8)&15 =====
__global__ __launch_bounds__(256) void k_out0T(const float* __restrict__ U32,
                                               float* __restrict__ out){
    __shared__ float tile[16][257];
    int tid = threadIdx.x;
    int k  = blockIdx.y;
    int t0 = blockIdx.x * 256;
    #pragma unroll
    for (int cw = 0; cw < 16; cw++)
        tile[cw][tid] = U32[((size_t)(k * 16 + cw)) * 16384 + t0 + tid];
    __syncthreads();
    #pragma unroll
    for (int i = 0; i < 16; i++){
        int flat = i * 256 + tid;            // flat = dt*16 + ch
        int dt = flat >> 4, ch = flat & 15;
        int cw = (ch + 8) & 15;
        out[(size_t)k * 131072 + t0 * 16 + flat] = tile[cw][dt];
    }
}

// ===== transpose 2: out1[1048576 + t*128 + b] = W2[b][t] =====
__global__ __launch_bounds__(256) void k_out1T(const float* __restrict__ U32,
                                               float* __restrict__ out){
    __shared__ float tile[128][65];
    int tid = threadIdx.x;
    int t0 = blockIdx.x * 64;
    #pragma unroll
    for (int i = 0; i < 32; i++){
        int flat = i * 256 + tid;
        int b = flat >> 6, dt = flat & 63;
        tile[b][dt] = U32[(size_t)b * 16384 + 8192 + t0 + dt];
    }
    __syncthreads();
    #pragma unroll
    for (int i = 0; i < 32; i++){
        int flat = i * 256 + tid;
        int dt = flat >> 7, b = flat & 127;
        out[1048576 + (size_t)(t0 + dt) * 128 + b] = tile[b][dt];
    }
}

// ===== omega history: out2 = Re(omega), 160 floats at 2097152 =====
__global__ void k_omega(const double* __restrict__ ndh, float* __restrict__ out){
    int t = threadIdx.x;
    if (t >= 160) return;
    int row = t >> 3, k = t & 7;
    double v = (row == 0) ? 0.0625 * (double)k
                          : ndh[(row - 1) * 16 + k] / ndh[(row - 1) * 16 + 8 + k];
    out[2097152 + t] = (float)v;
}

__global__ void k_zerond(double* __restrict__ q, int n){
    int i = blockIdx.x * blockDim.x + threadIdx.x;
    if (i < n) q[i] = 0.0;
}

extern "C" void kernel_launch(void* const* d_in, const int* in_sizes, int n_in,
                              void* d_out, int out_size, void* d_ws, size_t ws_size,
                              hipStream_t stream){
    const float* sig = (const float*)d_in[0];
    float* out = (float*)d_out;
    char* p = (char*)d_ws;
    // ws: U 8 MB | FPT 1 MB | D (NDH/BLK/GRP/REL/CNT) ~43 KB   (~9.05 MB total)
    float2* U   = (float2*)p;
    float2* FPT = (float2*)(p + (size_t)8 * 1024 * 1024);
    double* D   = (double*)(p + (size_t)9 * 1024 * 1024);

    // zero REL + ENTIRE CNT span: D[4656 .. 5440)
    k_zerond<<<dim3(4), dim3(256), 0, stream>>>(D + 4656, 784);
    k_stageA<<<dim3(16), dim3(1024), 65536, stream>>>(sig, FPT);
    k_vmd_all<<<dim3(VMD_BLOCKS), dim3(512), 0, stream>>>(FPT, U, D);
    k_stageCD<<<dim3(128), dim3(1024), 65536, stream>>>(U);
    k_out0T<<<dim3(32, 8), dim3(256), 0, stream>>>((const float*)U, out);
    k_out1T<<<dim3(128), dim3(256), 0, stream>>>((const float*)U, out);
    k_omega<<<dim3(1), dim3(256), 0, stream>>>(D, out);
}

// Round 13
// 416.674 us; speedup vs baseline: 20.2494x; 2.5342x over previous
//
#include <hip/hip_runtime.h>
#include <math.h>

#define NPAIR 131072          // 8192 freqs x 16 channels
#define STEPS 19
#define VMD_BLOCKS 128        // x 1024 threads = NPAIR
#define ND_BANKS 16

// XOR swizzle: spreads strided radix-8 writes across banks; keeps contiguous free
#define SW(a) ((a) ^ (((a) >> 5) & 31))

__device__ __forceinline__ float2 cadd(float2 a, float2 b){ return make_float2(a.x+b.x, a.y+b.y); }
__device__ __forceinline__ float2 csub(float2 a, float2 b){ return make_float2(a.x-b.x, a.y-b.y); }
__device__ __forceinline__ float2 cmul(float2 a, float2 b){
    return make_float2(a.x*b.x - a.y*b.y, a.x*b.y + a.y*b.x);
}
template<int SGN>
__device__ __forceinline__ float2 imul(float2 a){   // multiply by e^{SGN*i*pi/2}
    return (SGN > 0) ? make_float2(-a.y, a.x) : make_float2(a.y, -a.x);
}

// 8-point DFT: y_k = sum_r a_r e^{SGN*2pi i r k/8}
template<int SGN>
__device__ __forceinline__ void dft8(const float2* a, float2* y){
    const float C = 0.70710678118654752f;
    const float sg = (SGN > 0) ? 1.f : -1.f;
    float2 t0 = cadd(a[0], a[4]), t1 = csub(a[0], a[4]);
    float2 t2 = cadd(a[2], a[6]), t3 = imul<SGN>(csub(a[2], a[6]));
    float2 E0 = cadd(t0, t2), E2 = csub(t0, t2), E1 = cadd(t1, t3), E3 = csub(t1, t3);
    float2 s0 = cadd(a[1], a[5]), s1 = csub(a[1], a[5]);
    float2 s2 = cadd(a[3], a[7]), s3 = imul<SGN>(csub(a[3], a[7]));
    float2 O0 = cadd(s0, s2), O2 = csub(s0, s2), O1 = cadd(s1, s3), O3 = csub(s1, s3);
    float2 w1 = make_float2(C, sg * C), w3 = make_float2(-C, sg * C);
    float2 R0 = O0, R1 = cmul(O1, w1), R2 = imul<SGN>(O2), R3 = cmul(O3, w3);
    y[0] = cadd(E0, R0); y[4] = csub(E0, R0);
    y[1] = cadd(E1, R1); y[5] = csub(E1, R1);
    y[2] = cadd(E2, R2); y[6] = csub(E2, R2);
    y[3] = cadd(E3, R3); y[7] = csub(E3, R3);
}

// ===== in-LDS 8192-pt Stockham FFT: 4 radix-8 passes + 1 radix-2, 1024 threads =====
template<int SGN>
__device__ void lds_fft8192_r8(float2* lds, int tid){
    #pragma unroll
    for (int pi = 0; pi < 4; pi++){
        int ls = 3 * pi;
        int s  = 1 << ls;
        int nn = 8192 >> ls;
        int q = tid & (s - 1);
        float2 a[8], y[8];
        #pragma unroll
        for (int r = 0; r < 8; r++) a[r] = lds[SW(tid + (r << 10))];
        __syncthreads();
        dft8<SGN>(a, y);
        int p = tid >> ls;
        float ang = (float)(2 * p) / (float)nn;
        float sn, cs;
        sincospif(SGN > 0 ? ang : -ang, &sn, &cs);   // w = e^{SGN*2pi i p/nn}
        float2 w = make_float2(cs, sn);
        float2 wk = make_float2(1.f, 0.f);
        int o = q + ((tid - q) << 3);                 // q + 8*s*p
        lds[SW(o)] = y[0];
        #pragma unroll
        for (int k = 1; k < 8; k++){
            wk = cmul(wk, w);
            lds[SW(o + (k << ls))] = cmul(y[k], wk);
        }
        __syncthreads();
    }
    #pragma unroll
    for (int w4 = 0; w4 < 4; w4++){                   // final radix-2, twiddle-free
        int idx = (w4 << 10) + tid;
        float2 a = lds[SW(idx)], b = lds[SW(idx + 4096)];
        lds[SW(idx)]        = cadd(a, b);
        lds[SW(idx + 4096)] = csub(a, b);
    }
    __syncthreads();
}

// ===== stage A: mirror-extend + FFT16384 (split radix via 2x FFT8192) -> FPT =====
__global__ __launch_bounds__(1024) void k_stageA(const float* __restrict__ sig,
                                                 float2* __restrict__ FPT){
    extern __shared__ float2 lds[];
    int tid = threadIdx.x;
    int cw  = blockIdx.x;
    int cs  = (cw + 8) & 15;                 // fftshift over channel axis
    const float* sp = sig + cs * 8192;
    float2 regA[8];
    #pragma unroll
    for (int r = 0; r < 8; r++){             // even samples of mirrored extension
        int p = r * 1024 + tid;
        int x = 2 * p;
        int mx = (x < 4096) ? (4095 - x) : ((x < 12288) ? (x - 4096) : (20479 - x));
        lds[SW(p)] = make_float2(sp[mx], 0.f);
    }
    __syncthreads();
    lds_fft8192_r8<-1>(lds, tid);
    #pragma unroll
    for (int r = 0; r < 8; r++) regA[r] = lds[SW(r * 1024 + tid)];
    __syncthreads();
    #pragma unroll
    for (int r = 0; r < 8; r++){             // odd samples
        int p = r * 1024 + tid;
        int x = 2 * p + 1;
        int mx = (x < 4096) ? (4095 - x) : ((x < 12288) ? (x - 4096) : (20479 - x));
        lds[SW(p)] = make_float2(sp[mx], 0.f);
    }
    __syncthreads();
    lds_fft8192_r8<-1>(lds, tid);
    // combine: F[j] = A[j] + e^{-i pi j/8192} B[j]
    float sn, cn;
    sincospif(-(float)tid / 8192.0f, &sn, &cn);
    float2 w = make_float2(cn, sn);
    const float2 Wst = make_float2(0.92387953251128674f, -0.38268343236508977f); // e^{-i pi/8}
    #pragma unroll
    for (int q = 0; q < 8; q++){
        int j = q * 1024 + tid;
        float2 B = lds[SW(j)];
        float2 t = cmul(B, w);
        FPT[cw * 8192 + j] = make_float2(regA[q].x + t.x, regA[q].y + t.y);
        w = cmul(w, Wst);
    }
}

// ===== fused 19-step VMD: banked-atomic reduce + 2-hop distributed release =====
// 128 blocks x 1024 threads = NPAIR. Workspace doubles D:
//   NDB = D[0..4864)     banked sums: 19 steps x 16 banks x 16 doubles (also history)
//   CNT = (int*)&D[4864]:
//     group counters CNT[g*32], g<16 (8 blocks each) | root CNT[512]
//     root flag CNT[544] | group flags CNT[576 + g*32]
// Rules (R11/R12 lessons): poll RELAXED + ONE acquire (per-iter acquire = L2-inv storm);
// no O(N) serial work in leaders; release maintenance paid once per group IN PARALLEL.
__global__ __launch_bounds__(1024, 4) void k_vmd_all(const float2* __restrict__ FPT,
                                                     float2* __restrict__ U,
                                                     double* __restrict__ D){
    double* NDB = D;
    int*    CNT = (int*)(D + 4864);

    int tid = blockIdx.x * 1024 + threadIdx.x;  // [0,NPAIR), tid = cw*8192+j
    int j = tid & 8191;
    double fr = (double)j / 16384.0;
    float2 fv = FPT[tid];
    double fx = fv.x, fy = fv.y;
    float urx[8], ury[8];
    double om[8];
    #pragma unroll
    for (int k = 0; k < 8; k++){ urx[k] = 0.f; ury[k] = 0.f; om[k] = 0.0625 * (double)k; }
    __shared__ double lred[16][16];
    __shared__ double ndls[256];
    __shared__ double om_s[8];
    int lane = threadIdx.x & 63, wv = threadIdx.x >> 6;
    int mybank = (blockIdx.x & (ND_BANKS - 1)) * 16;
    int grp = blockIdx.x >> 3;                  // 16 groups of 8 blocks

    for (int step = 0; step < STEPS; step++){
        if (step > 0){
            #pragma unroll
            for (int k = 0; k < 8; k++) om[k] = om_s[k];
        }
        double sx = 0.0, sy = 0.0;
        #pragma unroll
        for (int k = 1; k < 8; k++){ sx += (double)urx[k]; sy += (double)ury[k]; }
        double lx = 0.0, ly = 0.0, nloc[8], dloc[8];
        #pragma unroll
        for (int k = 0; k < 8; k++){
            if (k > 0){ sx += lx - (double)urx[k]; sy += ly - (double)ury[k]; }
            double d = fr - om[k];
            double den = 1.0 + 2000.0 * d * d;
            double nx = (fx - sx) / den, ny = (fy - sy) / den;
            urx[k] = (float)nx; ury[k] = (float)ny;   // replicate complex64 carry
            lx = nx; ly = ny;
            double pw = nx * nx + ny * ny;
            nloc[k] = fr * pw; dloc[k] = pw;
        }
        #pragma unroll
        for (int k = 0; k < 8; k++){
            double a = nloc[k], b = dloc[k];
            for (int off = 32; off > 0; off >>= 1){
                a += __shfl_down(a, off);
                b += __shfl_down(b, off);
            }
            nloc[k] = a; dloc[k] = b;
        }
        if (lane == 0){
            #pragma unroll
            for (int k = 0; k < 8; k++){ lred[wv][k] = nloc[k]; lred[wv][8 + k] = dloc[k]; }
        }
        __syncthreads();
        if (threadIdx.x < 16){
            double sum = 0.0;
            #pragma unroll
            for (int w = 0; w < 16; w++) sum += lred[w][threadIdx.x];
            atomicAdd(&NDB[step * 256 + mybank + threadIdx.x], sum);  // 8 adds/address
        }
        __syncthreads();                        // ND adds complete before arrival RMW
        if (step < STEPS - 1){
            if (threadIdx.x == 0){
                int gtar = 8  * (step + 1);     // monotonic counters: no reset race
                int rtar = 16 * (step + 1);
                int old = __hip_atomic_fetch_add(&CNT[grp * 32], 1,
                                                 __ATOMIC_ACQ_REL, __HIP_MEMORY_SCOPE_AGENT);
                if (old == gtar - 1){           // group-last
                    int rold = __hip_atomic_fetch_add(&CNT[512], 1,
                                                      __ATOMIC_ACQ_REL, __HIP_MEMORY_SCOPE_AGENT);
                    if (rold == rtar - 1){      // root-last: single release publish
                        __hip_atomic_store(&CNT[544], step + 1,
                                           __ATOMIC_RELEASE, __HIP_MEMORY_SCOPE_AGENT);
                    } else {                    // other group-lasts: wait on root flag
                        while (__hip_atomic_load(&CNT[544], __ATOMIC_RELAXED,
                                                 __HIP_MEMORY_SCOPE_AGENT) <= step)
                            __builtin_amdgcn_s_sleep(2);
                        (void)__hip_atomic_load(&CNT[544], __ATOMIC_ACQUIRE,
                                                __HIP_MEMORY_SCOPE_AGENT);
                    }
                    // fan-out: 16 release stores happen IN PARALLEL across group-lasts
                    __hip_atomic_store(&CNT[576 + grp * 32], step + 1,
                                       __ATOMIC_RELEASE, __HIP_MEMORY_SCOPE_AGENT);
                } else {                        // members: wait on own group flag
                    while (__hip_atomic_load(&CNT[576 + grp * 32], __ATOMIC_RELAXED,
                                             __HIP_MEMORY_SCOPE_AGENT) <= step)
                        __builtin_amdgcn_s_sleep(2);
                    (void)__hip_atomic_load(&CNT[576 + grp * 32], __ATOMIC_ACQUIRE,
                                            __HIP_MEMORY_SCOPE_AGENT);
                }
            }
            __syncthreads();
            // parallel readback: 256 threads fetch one double each, sum in LDS
            if (threadIdx.x < 256)
                ndls[threadIdx.x] = __hip_atomic_load(&NDB[step * 256 + threadIdx.x],
                                                      __ATOMIC_RELAXED, __HIP_MEMORY_SCOPE_AGENT);
            __syncthreads();
            if (threadIdx.x < 8){
                double n_ = 0.0, d_ = 0.0;
                #pragma unroll
                for (int bk = 0; bk < ND_BANKS; bk++){
                    n_ += ndls[bk * 16 + threadIdx.x];
                    d_ += ndls[bk * 16 + 8 + threadIdx.x];
                }
                om_s[threadIdx.x] = n_ / d_;
            }
            __syncthreads();
        }
    }
    #pragma unroll
    for (int k = 0; k < 8; k++) U[k * NPAIR + tid] = make_float2(urx[k], ury[k]);
}

// ===== stage C+D: hermitian iFFT16384 -> slice -> FFT8192; results into own U slice =====
// After: U32[b*16384 + t] = y[t];  U32[b*16384 + 8192 + t] = Re(Yf[(t+4096) mod 8192])
__global__ __launch_bounds__(1024) void k_stageCD(float2* __restrict__ U){
    extern __shared__ float2 lds[];
    int tid = threadIdx.x;
    int b = blockIdx.x;                      // b = k*16 + cw
    const float2* pos = U + b * 8192;
    float* slice = (float*)(U) + (size_t)b * 16384;
    const float inv = 1.0f / 16384.0f;
    float2 regA[8];
    #pragma unroll
    for (int r = 0; r < 8; r++){             // v_even[p] = v[2p] (hermitian map)
        int p = r * 1024 + tid;
        int m = 2 * p;
        int jj; bool cj;
        if (m == 0)          { jj = 0;         cj = true;  }
        else if (m <= 8191)  { jj = m;         cj = false; }
        else if (m == 8192)  { jj = 8191;      cj = true;  }
        else                 { jj = 16384 - m; cj = true;  }
        float2 pv = pos[jj];
        lds[SW(p)] = make_float2(pv.x, cj ? -pv.y : pv.y);
    }
    __syncthreads();
    lds_fft8192_r8<1>(lds, tid);
    #pragma unroll
    for (int r = 0; r < 8; r++) regA[r] = lds[SW(r * 1024 + tid)];
    __syncthreads();
    #pragma unroll
    for (int r = 0; r < 8; r++){             // v_odd[p] = v[2p+1]
        int p = r * 1024 + tid;
        int m = 2 * p + 1;
        int jj; bool cj;
        if (m <= 8191) { jj = m;         cj = false; }
        else           { jj = 16384 - m; cj = true;  }
        float2 pv = pos[jj];
        lds[SW(p)] = make_float2(pv.x, cj ? -pv.y : pv.y);
    }
    __syncthreads();
    lds_fft8192_r8<1>(lds, tid);
    // combine -> y[t], coalesced write into own slice (all pos reads done)
    float yreg[8];
    float sn, cn;
    sincospif((float)(4096 + tid) / 8192.0f, &sn, &cn);
    float2 w = make_float2(cn, sn);
    const float2 Wst = make_float2(0.92387953251128674f, 0.38268343236508977f);  // e^{+i pi/8}
    #pragma unroll
    for (int q = 0; q < 8; q++){
        int t = q * 1024 + tid;
        int r = (q + 4) & 7;                 // (t+4096) mod 8192 block
        float2 A = regA[r];
        float2 B = lds[SW(r * 1024 + tid)];
        float2 tw = cmul(B, w);
        float yv = (A.x + tw.x) * inv;
        yreg[q] = yv;
        slice[t] = yv;
        w = cmul(w, Wst);
    }
    __syncthreads();
    #pragma unroll
    for (int q = 0; q < 8; q++) lds[SW(q * 1024 + tid)] = make_float2(yreg[q], 0.f);
    __syncthreads();
    lds_fft8192_r8<-1>(lds, tid);            // forward FFT8192 of y
    #pragma unroll
    for (int q = 0; q < 8; q++){
        int t = q * 1024 + tid;
        float2 Y = lds[SW(((q + 4) & 7) * 1024 + tid)];
        slice[8192 + t] = Y.x;               // Re(Yf[(t+4096) mod 8192]), coalesced
    }
}

// ===== transpose 1: out0[(k*8192+t)*16 + ch] = y[k*16+cw][t], ch=(cw+8)&15 =====
__global__ __launch_bounds__(256) void k_out0T(const float* __restrict__ U32,
                                               float* __restrict__ out){
    __shared__ float tile[16][257];
    int tid = threadIdx.x;
    int k  = blockIdx.y;
    int t0 = blockIdx.x * 256;
    #pragma unroll
    for (int cw = 0; cw < 16; cw++)
        tile[cw][tid] = U32[((size_t)(k * 16 + cw)) * 16384 + t0 + tid];
    __syncthreads();
    #pragma unroll
    for (int i = 0; i < 16; i++){
        int flat = i * 256 + tid;            // flat = dt*16 + ch
        int dt = flat >> 4, ch = flat & 15;
        int cw = (ch + 8) & 15;
        out[(size_t)k * 131072 + t0 * 16 + flat] = tile[cw][dt];
    }
}

// ===== transpose 2: out1[1048576 + t*128 + b] = W2[b][t] =====
__global__ __launch_bounds__(256) void k_out1T(const float* __restrict__ U32,
                                               float* __restrict__ out){
    __shared__ float tile[128][65];
    int tid = threadIdx.x;
    int t0 = blockIdx.x * 64;
    #pragma unroll
    for (int i = 0; i < 32; i++){
        int flat = i * 256 + tid;
        int b = flat >> 6, dt = flat & 63;
        tile[b][dt] = U32[(size_t)b * 16384 + 8192 + t0 + dt];
    }
    __syncthreads();
    #pragma unroll
    for (int i = 0; i < 32; i++){
        int flat = i * 256 + tid;
        int dt = flat >> 7, b = flat & 127;
        out[1048576 + (size_t)(t0 + dt) * 128 + b] = tile[b][dt];
    }
}

// ===== omega history: out2 = Re(omega), 160 floats at 2097152 =====
__global__ void k_omega(const double* __restrict__ ndb, float* __restrict__ out){
    int t = threadIdx.x;
    if (t >= 160) return;
    int row = t >> 3, k = t & 7;
    double v;
    if (row == 0){
        v = 0.0625 * (double)k;
    } else {
        const double* r = ndb + (row - 1) * 256;
        double n_ = 0.0, d_ = 0.0;
        #pragma unroll
        for (int bk = 0; bk < ND_BANKS; bk++){ n_ += r[bk * 16 + k]; d_ += r[bk * 16 + 8 + k]; }
        v = n_ / d_;
    }
    out[2097152 + t] = (float)v;
}

__global__ void k_zerond(double* __restrict__ q, int n){
    int i = blockIdx.x * blockDim.x + threadIdx.x;
    if (i < n) q[i] = 0.0;
}

extern "C" void kernel_launch(void* const* d_in, const int* in_sizes, int n_in,
                              void* d_out, int out_size, void* d_ws, size_t ws_size,
                              hipStream_t stream){
    const float* sig = (const float*)d_in[0];
    float* out = (float*)d_out;
    char* p = (char*)d_ws;
    // ws: U 8 MB | FPT 1 MB | D (NDB banks + CNT/flags) ~43 KB  (~9.05 MB total)
    float2* U   = (float2*)p;
    float2* FPT = (float2*)(p + (size_t)8 * 1024 * 1024);
    double* D   = (double*)(p + (size_t)9 * 1024 * 1024);

    // zero NDB D[0..4864) + full CNT/flag span D[4864..5400)
    k_zerond<<<dim3(22), dim3(256), 0, stream>>>(D, 5400);
    k_stageA<<<dim3(16), dim3(1024), 65536, stream>>>(sig, FPT);
    k_vmd_all<<<dim3(VMD_BLOCKS), dim3(1024), 0, stream>>>(FPT, U, D);
    k_stageCD<<<dim3(128), dim3(1024), 65536, stream>>>(U);
    k_out0T<<<dim3(32, 8), dim3(256), 0, stream>>>((const float*)U, out);
    k_out1T<<<dim3(128), dim3(256), 0, stream>>>((const float*)U, out);
    k_omega<<<dim3(1), dim3(256), 0, stream>>>(D, out);
}

// Round 14
// 415.895 us; speedup vs baseline: 20.2873x; 1.0019x over previous
//
#include <hip/hip_runtime.h>
#include <math.h>

#define NPAIR 131072          // 8192 freqs x 16 channels
#define STEPS 19
#define VMD_BLOCKS 128        // x 1024 threads = NPAIR
#define ND_BANKS 16

// XOR swizzle: spreads strided radix-8 writes across banks; keeps contiguous free
#define SW(a) ((a) ^ (((a) >> 5) & 31))

__device__ __forceinline__ float2 cadd(float2 a, float2 b){ return make_float2(a.x+b.x, a.y+b.y); }
__device__ __forceinline__ float2 csub(float2 a, float2 b){ return make_float2(a.x-b.x, a.y-b.y); }
__device__ __forceinline__ float2 cmul(float2 a, float2 b){
    return make_float2(a.x*b.x - a.y*b.y, a.x*b.y + a.y*b.x);
}
template<int SGN>
__device__ __forceinline__ float2 imul(float2 a){   // multiply by e^{SGN*i*pi/2}
    return (SGN > 0) ? make_float2(-a.y, a.x) : make_float2(a.y, -a.x);
}

// 8-point DFT: y_k = sum_r a_r e^{SGN*2pi i r k/8}
template<int SGN>
__device__ __forceinline__ void dft8(const float2* a, float2* y){
    const float C = 0.70710678118654752f;
    const float sg = (SGN > 0) ? 1.f : -1.f;
    float2 t0 = cadd(a[0], a[4]), t1 = csub(a[0], a[4]);
    float2 t2 = cadd(a[2], a[6]), t3 = imul<SGN>(csub(a[2], a[6]));
    float2 E0 = cadd(t0, t2), E2 = csub(t0, t2), E1 = cadd(t1, t3), E3 = csub(t1, t3);
    float2 s0 = cadd(a[1], a[5]), s1 = csub(a[1], a[5]);
    float2 s2 = cadd(a[3], a[7]), s3 = imul<SGN>(csub(a[3], a[7]));
    float2 O0 = cadd(s0, s2), O2 = csub(s0, s2), O1 = cadd(s1, s3), O3 = csub(s1, s3);
    float2 w1 = make_float2(C, sg * C), w3 = make_float2(-C, sg * C);
    float2 R0 = O0, R1 = cmul(O1, w1), R2 = imul<SGN>(O2), R3 = cmul(O3, w3);
    y[0] = cadd(E0, R0); y[4] = csub(E0, R0);
    y[1] = cadd(E1, R1); y[5] = csub(E1, R1);
    y[2] = cadd(E2, R2); y[6] = csub(E2, R2);
    y[3] = cadd(E3, R3); y[7] = csub(E3, R3);
}

// ===== in-LDS 8192-pt Stockham FFT: 4 radix-8 passes + 1 radix-2, 1024 threads =====
template<int SGN>
__device__ void lds_fft8192_r8(float2* lds, int tid){
    #pragma unroll
    for (int pi = 0; pi < 4; pi++){
        int ls = 3 * pi;
        int s  = 1 << ls;
        int nn = 8192 >> ls;
        int q = tid & (s - 1);
        float2 a[8], y[8];
        #pragma unroll
        for (int r = 0; r < 8; r++) a[r] = lds[SW(tid + (r << 10))];
        __syncthreads();
        dft8<SGN>(a, y);
        int p = tid >> ls;
        float ang = (float)(2 * p) / (float)nn;
        float sn, cs;
        sincospif(SGN > 0 ? ang : -ang, &sn, &cs);   // w = e^{SGN*2pi i p/nn}
        float2 w = make_float2(cs, sn);
        float2 wk = make_float2(1.f, 0.f);
        int o = q + ((tid - q) << 3);                 // q + 8*s*p
        lds[SW(o)] = y[0];
        #pragma unroll
        for (int k = 1; k < 8; k++){
            wk = cmul(wk, w);
            lds[SW(o + (k << ls))] = cmul(y[k], wk);
        }
        __syncthreads();
    }
    #pragma unroll
    for (int w4 = 0; w4 < 4; w4++){                   // final radix-2, twiddle-free
        int idx = (w4 << 10) + tid;
        float2 a = lds[SW(idx)], b = lds[SW(idx + 4096)];
        lds[SW(idx)]        = cadd(a, b);
        lds[SW(idx + 4096)] = csub(a, b);
    }
    __syncthreads();
}

// ===== stage A: mirror-extend + FFT16384 (split radix via 2x FFT8192) -> FPT =====
__global__ __launch_bounds__(1024) void k_stageA(const float* __restrict__ sig,
                                                 float2* __restrict__ FPT){
    extern __shared__ float2 lds[];
    int tid = threadIdx.x;
    int cw  = blockIdx.x;
    int cs  = (cw + 8) & 15;                 // fftshift over channel axis
    const float* sp = sig + cs * 8192;
    float2 regA[8];
    #pragma unroll
    for (int r = 0; r < 8; r++){             // even samples of mirrored extension
        int p = r * 1024 + tid;
        int x = 2 * p;
        int mx = (x < 4096) ? (4095 - x) : ((x < 12288) ? (x - 4096) : (20479 - x));
        lds[SW(p)] = make_float2(sp[mx], 0.f);
    }
    __syncthreads();
    lds_fft8192_r8<-1>(lds, tid);
    #pragma unroll
    for (int r = 0; r < 8; r++) regA[r] = lds[SW(r * 1024 + tid)];
    __syncthreads();
    #pragma unroll
    for (int r = 0; r < 8; r++){             // odd samples
        int p = r * 1024 + tid;
        int x = 2 * p + 1;
        int mx = (x < 4096) ? (4095 - x) : ((x < 12288) ? (x - 4096) : (20479 - x));
        lds[SW(p)] = make_float2(sp[mx], 0.f);
    }
    __syncthreads();
    lds_fft8192_r8<-1>(lds, tid);
    // combine: F[j] = A[j] + e^{-i pi j/8192} B[j]
    float sn, cn;
    sincospif(-(float)tid / 8192.0f, &sn, &cn);
    float2 w = make_float2(cn, sn);
    const float2 Wst = make_float2(0.92387953251128674f, -0.38268343236508977f); // e^{-i pi/8}
    #pragma unroll
    for (int q = 0; q < 8; q++){
        int j = q * 1024 + tid;
        float2 B = lds[SW(j)];
        float2 t = cmul(B, w);
        FPT[cw * 8192 + j] = make_float2(regA[q].x + t.x, regA[q].y + t.y);
        w = cmul(w, Wst);
    }
}

// ===== fused 19-step VMD: banked-atomic reduce + 2-hop distributed release =====
// 128 blocks x 1024 threads = NPAIR. Workspace doubles D:
//   NDB = D[0..4864)     banked sums: 19 steps x 16 banks x 16 doubles (also history)
//   CNT = (int*)&D[4864]:
//     group counters CNT[g*32], g<16 (8 blocks each) | root CNT[512]
//     root flag CNT[544] | group flags CNT[576 + g*32]
// Lessons: R11 poll RELAXED + ONE acquire; R12 no O(N) serial leader work;
// R13 launch_bounds(1024,4) -> 64-VGPR cap -> 28 regs spilled -> 50 MB scratch
// writes -> HBM-bound. (1024,1) gives the 128-VGPR cap this kernel needs (~92).
__global__ __launch_bounds__(1024, 1) void k_vmd_all(const float2* __restrict__ FPT,
                                                     float2* __restrict__ U,
                                                     double* __restrict__ D){
    double* NDB = D;
    int*    CNT = (int*)(D + 4864);

    int tid = blockIdx.x * 1024 + threadIdx.x;  // [0,NPAIR), tid = cw*8192+j
    int j = tid & 8191;
    double fr = (double)j / 16384.0;
    float2 fv = FPT[tid];
    double fx = fv.x, fy = fv.y;
    float urx[8], ury[8];
    double om[8];
    #pragma unroll
    for (int k = 0; k < 8; k++){ urx[k] = 0.f; ury[k] = 0.f; om[k] = 0.0625 * (double)k; }
    __shared__ double lred[16][16];
    __shared__ double ndls[256];
    __shared__ double om_s[8];
    int lane = threadIdx.x & 63, wv = threadIdx.x >> 6;
    int mybank = (blockIdx.x & (ND_BANKS - 1)) * 16;
    int grp = blockIdx.x >> 3;                  // 16 groups of 8 blocks

    for (int step = 0; step < STEPS; step++){
        if (step > 0){
            #pragma unroll
            for (int k = 0; k < 8; k++) om[k] = om_s[k];
        }
        double sx = 0.0, sy = 0.0;
        #pragma unroll
        for (int k = 1; k < 8; k++){ sx += (double)urx[k]; sy += (double)ury[k]; }
        double lx = 0.0, ly = 0.0, nloc[8], dloc[8];
        #pragma unroll
        for (int k = 0; k < 8; k++){
            if (k > 0){ sx += lx - (double)urx[k]; sy += ly - (double)ury[k]; }
            double d = fr - om[k];
            double den = 1.0 + 2000.0 * d * d;
            double nx = (fx - sx) / den, ny = (fy - sy) / den;
            urx[k] = (float)nx; ury[k] = (float)ny;   // replicate complex64 carry
            lx = nx; ly = ny;
            double pw = nx * nx + ny * ny;
            nloc[k] = fr * pw; dloc[k] = pw;
        }
        #pragma unroll
        for (int k = 0; k < 8; k++){
            double a = nloc[k], b = dloc[k];
            for (int off = 32; off > 0; off >>= 1){
                a += __shfl_down(a, off);
                b += __shfl_down(b, off);
            }
            nloc[k] = a; dloc[k] = b;
        }
        if (lane == 0){
            #pragma unroll
            for (int k = 0; k < 8; k++){ lred[wv][k] = nloc[k]; lred[wv][8 + k] = dloc[k]; }
        }
        __syncthreads();
        if (threadIdx.x < 16){
            double sum = 0.0;
            #pragma unroll
            for (int w = 0; w < 16; w++) sum += lred[w][threadIdx.x];
            atomicAdd(&NDB[step * 256 + mybank + threadIdx.x], sum);  // 8 adds/address
        }
        __syncthreads();                        // ND adds complete before arrival RMW
        if (step < STEPS - 1){
            if (threadIdx.x == 0){
                int gtar = 8  * (step + 1);     // monotonic counters: no reset race
                int rtar = 16 * (step + 1);
                int old = __hip_atomic_fetch_add(&CNT[grp * 32], 1,
                                                 __ATOMIC_ACQ_REL, __HIP_MEMORY_SCOPE_AGENT);
                if (old == gtar - 1){           // group-last
                    int rold = __hip_atomic_fetch_add(&CNT[512], 1,
                                                      __ATOMIC_ACQ_REL, __HIP_MEMORY_SCOPE_AGENT);
                    if (rold == rtar - 1){      // root-last: single release publish
                        __hip_atomic_store(&CNT[544], step + 1,
                                           __ATOMIC_RELEASE, __HIP_MEMORY_SCOPE_AGENT);
                    } else {                    // other group-lasts: wait on root flag
                        while (__hip_atomic_load(&CNT[544], __ATOMIC_RELAXED,
                                                 __HIP_MEMORY_SCOPE_AGENT) <= step)
                            __builtin_amdgcn_s_sleep(2);
                        (void)__hip_atomic_load(&CNT[544], __ATOMIC_ACQUIRE,
                                                __HIP_MEMORY_SCOPE_AGENT);
                    }
                    // fan-out: 16 release stores happen IN PARALLEL across group-lasts
                    __hip_atomic_store(&CNT[576 + grp * 32], step + 1,
                                       __ATOMIC_RELEASE, __HIP_MEMORY_SCOPE_AGENT);
                } else {                        // members: wait on own group flag
                    while (__hip_atomic_load(&CNT[576 + grp * 32], __ATOMIC_RELAXED,
                                             __HIP_MEMORY_SCOPE_AGENT) <= step)
                        __builtin_amdgcn_s_sleep(2);
                    (void)__hip_atomic_load(&CNT[576 + grp * 32], __ATOMIC_ACQUIRE,
                                            __HIP_MEMORY_SCOPE_AGENT);
                }
            }
            __syncthreads();
            // parallel readback: 256 threads fetch one double each, sum in LDS
            if (threadIdx.x < 256)
                ndls[threadIdx.x] = __hip_atomic_load(&NDB[step * 256 + threadIdx.x],
                                                      __ATOMIC_RELAXED, __HIP_MEMORY_SCOPE_AGENT);
            __syncthreads();
            if (threadIdx.x < 8){
                double n_ = 0.0, d_ = 0.0;
                #pragma unroll
                for (int bk = 0; bk < ND_BANKS; bk++){
                    n_ += ndls[bk * 16 + threadIdx.x];
                    d_ += ndls[bk * 16 + 8 + threadIdx.x];
                }
                om_s[threadIdx.x] = n_ / d_;
            }
            __syncthreads();
        }
    }
    #pragma unroll
    for (int k = 0; k < 8; k++) U[k * NPAIR + tid] = make_float2(urx[k], ury[k]);
}

// ===== stage C+D: hermitian iFFT16384 -> slice -> FFT8192; results into own U slice =====
// After: U32[b*16384 + t] = y[t];  U32[b*16384 + 8192 + t] = Re(Yf[(t+4096) mod 8192])
__global__ __launch_bounds__(1024) void k_stageCD(float2* __restrict__ U){
    extern __shared__ float2 lds[];
    int tid = threadIdx.x;
    int b = blockIdx.x;                      // b = k*16 + cw
    const float2* pos = U + b * 8192;
    float* slice = (float*)(U) + (size_t)b * 16384;
    const float inv = 1.0f / 16384.0f;
    float2 regA[8];
    #pragma unroll
    for (int r = 0; r < 8; r++){             // v_even[p] = v[2p] (hermitian map)
        int p = r * 1024 + tid;
        int m = 2 * p;
        int jj; bool cj;
        if (m == 0)          { jj = 0;         cj = true;  }
        else if (m <= 8191)  { jj = m;         cj = false; }
        else if (m == 8192)  { jj = 8191;      cj = true;  }
        else                 { jj = 16384 - m; cj = true;  }
        float2 pv = pos[jj];
        lds[SW(p)] = make_float2(pv.x, cj ? -pv.y : pv.y);
    }
    __syncthreads();
    lds_fft8192_r8<1>(lds, tid);
    #pragma unroll
    for (int r = 0; r < 8; r++) regA[r] = lds[SW(r * 1024 + tid)];
    __syncthreads();
    #pragma unroll
    for (int r = 0; r < 8; r++){             // v_odd[p] = v[2p+1]
        int p = r * 1024 + tid;
        int m = 2 * p + 1;
        int jj; bool cj;
        if (m <= 8191) { jj = m;         cj = false; }
        else           { jj = 16384 - m; cj = true;  }
        float2 pv = pos[jj];
        lds[SW(p)] = make_float2(pv.x, cj ? -pv.y : pv.y);
    }
    __syncthreads();
    lds_fft8192_r8<1>(lds, tid);
    // combine -> y[t], coalesced write into own slice (all pos reads done)
    float yreg[8];
    float sn, cn;
    sincospif((float)(4096 + tid) / 8192.0f, &sn, &cn);
    float2 w = make_float2(cn, sn);
    const float2 Wst = make_float2(0.92387953251128674f, 0.38268343236508977f);  // e^{+i pi/8}
    #pragma unroll
    for (int q = 0; q < 8; q++){
        int t = q * 1024 + tid;
        int r = (q + 4) & 7;                 // (t+4096) mod 8192 block
        float2 A = regA[r];
        float2 B = lds[SW(r * 1024 + tid)];
        float2 tw = cmul(B, w);
        float yv = (A.x + tw.x) * inv;
        yreg[q] = yv;
        slice[t] = yv;
        w = cmul(w, Wst);
    }
    __syncthreads();
    #pragma unroll
    for (int q = 0; q < 8; q++) lds[SW(q * 1024 + tid)] = make_float2(yreg[q], 0.f);
    __syncthreads();
    lds_fft8192_r8<-1>(lds, tid);            // forward FFT8192 of y
    #pragma unroll
    for (int q = 0; q < 8; q++){
        int t = q * 1024 + tid;
        float2 Y = lds[SW(((q + 4) & 7) * 1024 + tid)];
        slice[8192 + t] = Y.x;               // Re(Yf[(t+4096) mod 8192]), coalesced
    }
}

// ===== transpose 1: out0[(k*8192+t)*16 + ch] = y[k*16+cw][t], ch=(cw+8)&15 =====
__global__ __launch_bounds__(256) void k_out0T(const float* __restrict__ U32,
                                               float* __restrict__ out){
    __shared__ float tile[16][257];
    int tid = threadIdx.x;
    int k  = blockIdx.y;
    int t0 = blockIdx.x * 256;
    #pragma unroll
    for (int cw = 0; cw < 16; cw++)
        tile[cw][tid] = U32[((size_t)(k * 16 + cw)) * 16384 + t0 + tid];
    __syncthreads();
    #pragma unroll
    for (int i = 0; i < 16; i++){
        int flat = i * 256 + tid;            // flat = dt*16 + ch
        int dt = flat >> 4, ch = flat & 15;
        int cw = (ch + 8) & 15;
        out[(size_t)k * 131072 + t0 * 16 + flat] = tile[cw][dt];
    }
}

// ===== transpose 2: out1[1048576 + t*128 + b] = W2[b][t] =====
__global__ __launch_bounds__(256) void k_out1T(const float* __restrict__ U32,
                                               float* __restrict__ out){
    __shared__ float tile[128][65];
    int tid = threadIdx.x;
    int t0 = blockIdx.x * 64;
    #pragma unroll
    for (int i = 0; i < 32; i++){
        int flat = i * 256 + tid;
        int b = flat >> 6, dt = flat & 63;
        tile[b][dt] = U32[(size_t)b * 16384 + 8192 + t0 + dt];
    }
    __syncthreads();
    #pragma unroll
    for (int i = 0; i < 32; i++){
        int flat = i * 256 + tid;
        int dt = flat >> 7, b = flat & 127;
        out[1048576 + (size_t)(t0 + dt) * 128 + b] = tile[b][dt];
    }
}

// ===== omega history: out2 = Re(omega), 160 floats at 2097152 =====
__global__ void k_omega(const double* __restrict__ ndb, float* __restrict__ out){
    int t = threadIdx.x;
    if (t >= 160) return;
    int row = t >> 3, k = t & 7;
    double v;
    if (row == 0){
        v = 0.0625 * (double)k;
    } else {
        const double* r = ndb + (row - 1) * 256;
        double n_ = 0.0, d_ = 0.0;
        #pragma unroll
        for (int bk = 0; bk < ND_BANKS; bk++){ n_ += r[bk * 16 + k]; d_ += r[bk * 16 + 8 + k]; }
        v = n_ / d_;
    }
    out[2097152 + t] = (float)v;
}

__global__ void k_zerond(double* __restrict__ q, int n){
    int i = blockIdx.x * blockDim.x + threadIdx.x;
    if (i < n) q[i] = 0.0;
}

extern "C" void kernel_launch(void* const* d_in, const int* in_sizes, int n_in,
                              void* d_out, int out_size, void* d_ws, size_t ws_size,
                              hipStream_t stream){
    const float* sig = (const float*)d_in[0];
    float* out = (float*)d_out;
    char* p = (char*)d_ws;
    // ws: U 8 MB | FPT 1 MB | D (NDB banks + CNT/flags) ~43 KB  (~9.05 MB total)
    float2* U   = (float2*)p;
    float2* FPT = (float2*)(p + (size_t)8 * 1024 * 1024);
    double* D   = (double*)(p + (size_t)9 * 1024 * 1024);

    // zero NDB D[0..4864) + full CNT/flag span D[4864..5400)
    k_zerond<<<dim3(22), dim3(256), 0, stream>>>(D, 5400);
    k_stageA<<<dim3(16), dim3(1024), 65536, stream>>>(sig, FPT);
    k_vmd_all<<<dim3(VMD_BLOCKS), dim3(1024), 0, stream>>>(FPT, U, D);
    k_stageCD<<<dim3(128), dim3(1024), 65536, stream>>>(U);
    k_out0T<<<dim3(32, 8), dim3(256), 0, stream>>>((const float*)U, out);
    k_out1T<<<dim3(128), dim3(256), 0, stream>>>((const float*)U, out);
    k_omega<<<dim3(1), dim3(256), 0, stream>>>(D, out);
}

// Round 15
// 351.836 us; speedup vs baseline: 23.9810x; 1.1821x over previous
//
#include <hip/hip_runtime.h>
#include <math.h>

#define NPAIR 131072          // 8192 freqs x 16 channels
#define STEPS 19
#define VMD_BLOCKS 256        // x 512 threads = NPAIR
#define ND_BANKS 16

// XOR swizzle: spreads strided radix-8 writes across banks; keeps contiguous free
#define SW(a) ((a) ^ (((a) >> 5) & 31))

__device__ __forceinline__ float2 cadd(float2 a, float2 b){ return make_float2(a.x+b.x, a.y+b.y); }
__device__ __forceinline__ float2 csub(float2 a, float2 b){ return make_float2(a.x-b.x, a.y-b.y); }
__device__ __forceinline__ float2 cmul(float2 a, float2 b){
    return make_float2(a.x*b.x - a.y*b.y, a.x*b.y + a.y*b.x);
}
template<int SGN>
__device__ __forceinline__ float2 imul(float2 a){   // multiply by e^{SGN*i*pi/2}
    return (SGN > 0) ? make_float2(-a.y, a.x) : make_float2(a.y, -a.x);
}

// 8-point DFT: y_k = sum_r a_r e^{SGN*2pi i r k/8}
template<int SGN>
__device__ __forceinline__ void dft8(const float2* a, float2* y){
    const float C = 0.70710678118654752f;
    const float sg = (SGN > 0) ? 1.f : -1.f;
    float2 t0 = cadd(a[0], a[4]), t1 = csub(a[0], a[4]);
    float2 t2 = cadd(a[2], a[6]), t3 = imul<SGN>(csub(a[2], a[6]));
    float2 E0 = cadd(t0, t2), E2 = csub(t0, t2), E1 = cadd(t1, t3), E3 = csub(t1, t3);
    float2 s0 = cadd(a[1], a[5]), s1 = csub(a[1], a[5]);
    float2 s2 = cadd(a[3], a[7]), s3 = imul<SGN>(csub(a[3], a[7]));
    float2 O0 = cadd(s0, s2), O2 = csub(s0, s2), O1 = cadd(s1, s3), O3 = csub(s1, s3);
    float2 w1 = make_float2(C, sg * C), w3 = make_float2(-C, sg * C);
    float2 R0 = O0, R1 = cmul(O1, w1), R2 = imul<SGN>(O2), R3 = cmul(O3, w3);
    y[0] = cadd(E0, R0); y[4] = csub(E0, R0);
    y[1] = cadd(E1, R1); y[5] = csub(E1, R1);
    y[2] = cadd(E2, R2); y[6] = csub(E2, R2);
    y[3] = cadd(E3, R3); y[7] = csub(E3, R3);
}

// ===== in-LDS 8192-pt Stockham FFT: 4 radix-8 passes + 1 radix-2, 1024 threads =====
template<int SGN>
__device__ void lds_fft8192_r8(float2* lds, int tid){
    #pragma unroll
    for (int pi = 0; pi < 4; pi++){
        int ls = 3 * pi;
        int s  = 1 << ls;
        int nn = 8192 >> ls;
        int q = tid & (s - 1);
        float2 a[8], y[8];
        #pragma unroll
        for (int r = 0; r < 8; r++) a[r] = lds[SW(tid + (r << 10))];
        __syncthreads();
        dft8<SGN>(a, y);
        int p = tid >> ls;
        float ang = (float)(2 * p) / (float)nn;
        float sn, cs;
        sincospif(SGN > 0 ? ang : -ang, &sn, &cs);   // w = e^{SGN*2pi i p/nn}
        float2 w = make_float2(cs, sn);
        float2 wk = make_float2(1.f, 0.f);
        int o = q + ((tid - q) << 3);                 // q + 8*s*p
        lds[SW(o)] = y[0];
        #pragma unroll
        for (int k = 1; k < 8; k++){
            wk = cmul(wk, w);
            lds[SW(o + (k << ls))] = cmul(y[k], wk);
        }
        __syncthreads();
    }
    #pragma unroll
    for (int w4 = 0; w4 < 4; w4++){                   // final radix-2, twiddle-free
        int idx = (w4 << 10) + tid;
        float2 a = lds[SW(idx)], b = lds[SW(idx + 4096)];
        lds[SW(idx)]        = cadd(a, b);
        lds[SW(idx + 4096)] = csub(a, b);
    }
    __syncthreads();
}

// ===== stage A: mirror-extend + FFT16384 (split radix via 2x FFT8192) -> FPT =====
__global__ __launch_bounds__(1024) void k_stageA(const float* __restrict__ sig,
                                                 float2* __restrict__ FPT){
    extern __shared__ float2 lds[];
    int tid = threadIdx.x;
    int cw  = blockIdx.x;
    int cs  = (cw + 8) & 15;                 // fftshift over channel axis
    const float* sp = sig + cs * 8192;
    float2 regA[8];
    #pragma unroll
    for (int r = 0; r < 8; r++){             // even samples of mirrored extension
        int p = r * 1024 + tid;
        int x = 2 * p;
        int mx = (x < 4096) ? (4095 - x) : ((x < 12288) ? (x - 4096) : (20479 - x));
        lds[SW(p)] = make_float2(sp[mx], 0.f);
    }
    __syncthreads();
    lds_fft8192_r8<-1>(lds, tid);
    #pragma unroll
    for (int r = 0; r < 8; r++) regA[r] = lds[SW(r * 1024 + tid)];
    __syncthreads();
    #pragma unroll
    for (int r = 0; r < 8; r++){             // odd samples
        int p = r * 1024 + tid;
        int x = 2 * p + 1;
        int mx = (x < 4096) ? (4095 - x) : ((x < 12288) ? (x - 4096) : (20479 - x));
        lds[SW(p)] = make_float2(sp[mx], 0.f);
    }
    __syncthreads();
    lds_fft8192_r8<-1>(lds, tid);
    // combine: F[j] = A[j] + e^{-i pi j/8192} B[j]
    float sn, cn;
    sincospif(-(float)tid / 8192.0f, &sn, &cn);
    float2 w = make_float2(cn, sn);
    const float2 Wst = make_float2(0.92387953251128674f, -0.38268343236508977f); // e^{-i pi/8}
    #pragma unroll
    for (int q = 0; q < 8; q++){
        int j = q * 1024 + tid;
        float2 B = lds[SW(j)];
        float2 t = cmul(B, w);
        FPT[cw * 8192 + j] = make_float2(regA[q].x + t.x, regA[q].y + t.y);
        w = cmul(w, Wst);
    }
}

// ===== fused 19-step VMD: banked-atomic reduce + 2-hop distributed release =====
// 256 blocks x 512 threads = NPAIR (512-thread blocks: R9/R12-proven ~92 VGPR, NO
// spill; R13/R14 showed 1024-thread blocks force a 64-VGPR cap -> 28 spilled regs
// -> 50 MB scratch writes -> HBM-bound at 316 us).
// Workspace doubles D:
//   NDB = D[0..4864)     banked sums: 19 steps x 16 banks x 16 doubles (also history)
//   CNT = (int*)&D[4864]:
//     group counters CNT[g*32], g<16 (16 blocks each) | root CNT[512]
//     root flag CNT[544] | group flags CNT[576 + g*32]
// Lessons: R11 poll RELAXED + ONE acquire (per-iter acquire = L2-inv storm);
// R12 no O(N) serial leader work; release maintenance paid per group IN PARALLEL.
__global__ __launch_bounds__(512, 2) void k_vmd_all(const float2* __restrict__ FPT,
                                                    float2* __restrict__ U,
                                                    double* __restrict__ D){
    double* NDB = D;
    int*    CNT = (int*)(D + 4864);

    int tid = blockIdx.x * 512 + threadIdx.x;   // [0,NPAIR), tid = cw*8192+j
    int j = tid & 8191;
    double fr = (double)j / 16384.0;
    float2 fv = FPT[tid];
    double fx = fv.x, fy = fv.y;
    float urx[8], ury[8];
    double om[8];
    #pragma unroll
    for (int k = 0; k < 8; k++){ urx[k] = 0.f; ury[k] = 0.f; om[k] = 0.0625 * (double)k; }
    __shared__ double lred[8][16];
    __shared__ double ndls[256];
    __shared__ double om_s[8];
    int lane = threadIdx.x & 63, wv = threadIdx.x >> 6;
    int mybank = (blockIdx.x & (ND_BANKS - 1)) * 16;
    int grp = blockIdx.x >> 4;                  // 16 groups of 16 blocks

    for (int step = 0; step < STEPS; step++){
        if (step > 0){
            #pragma unroll
            for (int k = 0; k < 8; k++) om[k] = om_s[k];
        }
        double sx = 0.0, sy = 0.0;
        #pragma unroll
        for (int k = 1; k < 8; k++){ sx += (double)urx[k]; sy += (double)ury[k]; }
        double lx = 0.0, ly = 0.0, nloc[8], dloc[8];
        #pragma unroll
        for (int k = 0; k < 8; k++){
            if (k > 0){ sx += lx - (double)urx[k]; sy += ly - (double)ury[k]; }
            double d = fr - om[k];
            double den = 1.0 + 2000.0 * d * d;
            double nx = (fx - sx) / den, ny = (fy - sy) / den;
            urx[k] = (float)nx; ury[k] = (float)ny;   // replicate complex64 carry
            lx = nx; ly = ny;
            double pw = nx * nx + ny * ny;
            nloc[k] = fr * pw; dloc[k] = pw;
        }
        #pragma unroll
        for (int k = 0; k < 8; k++){
            double a = nloc[k], b = dloc[k];
            for (int off = 32; off > 0; off >>= 1){
                a += __shfl_down(a, off);
                b += __shfl_down(b, off);
            }
            nloc[k] = a; dloc[k] = b;
        }
        if (lane == 0){
            #pragma unroll
            for (int k = 0; k < 8; k++){ lred[wv][k] = nloc[k]; lred[wv][8 + k] = dloc[k]; }
        }
        __syncthreads();
        if (threadIdx.x < 16){
            double sum = 0.0;
            #pragma unroll
            for (int w = 0; w < 8; w++) sum += lred[w][threadIdx.x];
            atomicAdd(&NDB[step * 256 + mybank + threadIdx.x], sum);  // 16 adds/address
        }
        __syncthreads();                        // ND adds complete before arrival RMW
        if (step < STEPS - 1){
            if (threadIdx.x == 0){
                int target = 16 * (step + 1);   // monotonic counters: no reset race
                int old = __hip_atomic_fetch_add(&CNT[grp * 32], 1,
                                                 __ATOMIC_ACQ_REL, __HIP_MEMORY_SCOPE_AGENT);
                if (old == target - 1){         // group-last
                    int rold = __hip_atomic_fetch_add(&CNT[512], 1,
                                                      __ATOMIC_ACQ_REL, __HIP_MEMORY_SCOPE_AGENT);
                    if (rold == target - 1){    // root-last: single release publish
                        __hip_atomic_store(&CNT[544], step + 1,
                                           __ATOMIC_RELEASE, __HIP_MEMORY_SCOPE_AGENT);
                    } else {                    // other group-lasts: wait on root flag
                        while (__hip_atomic_load(&CNT[544], __ATOMIC_RELAXED,
                                                 __HIP_MEMORY_SCOPE_AGENT) <= step)
                            __builtin_amdgcn_s_sleep(2);
                        (void)__hip_atomic_load(&CNT[544], __ATOMIC_ACQUIRE,
                                                __HIP_MEMORY_SCOPE_AGENT);
                    }
                    // fan-out: 16 release stores happen IN PARALLEL across group-lasts
                    __hip_atomic_store(&CNT[576 + grp * 32], step + 1,
                                       __ATOMIC_RELEASE, __HIP_MEMORY_SCOPE_AGENT);
                } else {                        // members: wait on own group flag
                    while (__hip_atomic_load(&CNT[576 + grp * 32], __ATOMIC_RELAXED,
                                             __HIP_MEMORY_SCOPE_AGENT) <= step)
                        __builtin_amdgcn_s_sleep(2);
                    (void)__hip_atomic_load(&CNT[576 + grp * 32], __ATOMIC_ACQUIRE,
                                            __HIP_MEMORY_SCOPE_AGENT);
                }
            }
            __syncthreads();
            // parallel readback: 256 threads fetch one double each, sum in LDS
            if (threadIdx.x < 256)
                ndls[threadIdx.x] = __hip_atomic_load(&NDB[step * 256 + threadIdx.x],
                                                      __ATOMIC_RELAXED, __HIP_MEMORY_SCOPE_AGENT);
            __syncthreads();
            if (threadIdx.x < 8){
                double n_ = 0.0, d_ = 0.0;
                #pragma unroll
                for (int bk = 0; bk < ND_BANKS; bk++){
                    n_ += ndls[bk * 16 + threadIdx.x];
                    d_ += ndls[bk * 16 + 8 + threadIdx.x];
                }
                om_s[threadIdx.x] = n_ / d_;
            }
            __syncthreads();
        }
    }
    #pragma unroll
    for (int k = 0; k < 8; k++) U[k * NPAIR + tid] = make_float2(urx[k], ury[k]);
}

// ===== stage C+D: hermitian iFFT16384 -> slice -> FFT8192; results into own U slice =====
// After: U32[b*16384 + t] = y[t];  U32[b*16384 + 8192 + t] = Re(Yf[(t+4096) mod 8192])
__global__ __launch_bounds__(1024) void k_stageCD(float2* __restrict__ U){
    extern __shared__ float2 lds[];
    int tid = threadIdx.x;
    int b = blockIdx.x;                      // b = k*16 + cw
    const float2* pos = U + b * 8192;
    float* slice = (float*)(U) + (size_t)b * 16384;
    const float inv = 1.0f / 16384.0f;
    float2 regA[8];
    #pragma unroll
    for (int r = 0; r < 8; r++){             // v_even[p] = v[2p] (hermitian map)
        int p = r * 1024 + tid;
        int m = 2 * p;
        int jj; bool cj;
        if (m == 0)          { jj = 0;         cj = true;  }
        else if (m <= 8191)  { jj = m;         cj = false; }
        else if (m == 8192)  { jj = 8191;      cj = true;  }
        else                 { jj = 16384 - m; cj = true;  }
        float2 pv = pos[jj];
        lds[SW(p)] = make_float2(pv.x, cj ? -pv.y : pv.y);
    }
    __syncthreads();
    lds_fft8192_r8<1>(lds, tid);
    #pragma unroll
    for (int r = 0; r < 8; r++) regA[r] = lds[SW(r * 1024 + tid)];
    __syncthreads();
    #pragma unroll
    for (int r = 0; r < 8; r++){             // v_odd[p] = v[2p+1]
        int p = r * 1024 + tid;
        int m = 2 * p + 1;
        int jj; bool cj;
        if (m <= 8191) { jj = m;         cj = false; }
        else           { jj = 16384 - m; cj = true;  }
        float2 pv = pos[jj];
        lds[SW(p)] = make_float2(pv.x, cj ? -pv.y : pv.y);
    }
    __syncthreads();
    lds_fft8192_r8<1>(lds, tid);
    // combine -> y[t], coalesced write into own slice (all pos reads done)
    float yreg[8];
    float sn, cn;
    sincospif((float)(4096 + tid) / 8192.0f, &sn, &cn);
    float2 w = make_float2(cn, sn);
    const float2 Wst = make_float2(0.92387953251128674f, 0.38268343236508977f);  // e^{+i pi/8}
    #pragma unroll
    for (int q = 0; q < 8; q++){
        int t = q * 1024 + tid;
        int r = (q + 4) & 7;                 // (t+4096) mod 8192 block
        float2 A = regA[r];
        float2 B = lds[SW(r * 1024 + tid)];
        float2 tw = cmul(B, w);
        float yv = (A.x + tw.x) * inv;
        yreg[q] = yv;
        slice[t] = yv;
        w = cmul(w, Wst);
    }
    __syncthreads();
    #pragma unroll
    for (int q = 0; q < 8; q++) lds[SW(q * 1024 + tid)] = make_float2(yreg[q], 0.f);
    __syncthreads();
    lds_fft8192_r8<-1>(lds, tid);            // forward FFT8192 of y
    #pragma unroll
    for (int q = 0; q < 8; q++){
        int t = q * 1024 + tid;
        float2 Y = lds[SW(((q + 4) & 7) * 1024 + tid)];
        slice[8192 + t] = Y.x;               // Re(Yf[(t+4096) mod 8192]), coalesced
    }
}

// ===== transpose 1: out0[(k*8192+t)*16 + ch] = y[k*16+cw][t], ch=(cw+8)&15 =====
__global__ __launch_bounds__(256) void k_out0T(const float* __restrict__ U32,
                                               float* __restrict__ out){
    __shared__ float tile[16][257];
    int tid = threadIdx.x;
    int k  = blockIdx.y;
    int t0 = blockIdx.x * 256;
    #pragma unroll
    for (int cw = 0; cw < 16; cw++)
        tile[cw][tid] = U32[((size_t)(k * 16 + cw)) * 16384 + t0 + tid];
    __syncthreads();
    #pragma unroll
    for (int i = 0; i < 16; i++){
        int flat = i * 256 + tid;            // flat = dt*16 + ch
        int dt = flat >> 4, ch = flat & 15;
        int cw = (ch + 8) & 15;
        out[(size_t)k * 131072 + t0 * 16 + flat] = tile[cw][dt];
    }
}

// ===== transpose 2: out1[1048576 + t*128 + b] = W2[b][t] =====
__global__ __launch_bounds__(256) void k_out1T(const float* __restrict__ U32,
                                               float* __restrict__ out){
    __shared__ float tile[128][65];
    int tid = threadIdx.x;
    int t0 = blockIdx.x * 64;
    #pragma unroll
    for (int i = 0; i < 32; i++){
        int flat = i * 256 + tid;
        int b = flat >> 6, dt = flat & 63;
        tile[b][dt] = U32[(size_t)b * 16384 + 8192 + t0 + dt];
    }
    __syncthreads();
    #pragma unroll
    for (int i = 0; i < 32; i++){
        int flat = i * 256 + tid;
        int dt = flat >> 7, b = flat & 127;
        out[1048576 + (size_t)(t0 + dt) * 128 + b] = tile[b][dt];
    }
}

// ===== omega history: out2 = Re(omega), 160 floats at 2097152 =====
__global__ void k_omega(const double* __restrict__ ndb, float* __restrict__ out){
    int t = threadIdx.x;
    if (t >= 160) return;
    int row = t >> 3, k = t & 7;
    double v;
    if (row == 0){
        v = 0.0625 * (double)k;
    } else {
        const double* r = ndb + (row - 1) * 256;
        double n_ = 0.0, d_ = 0.0;
        #pragma unroll
        for (int bk = 0; bk < ND_BANKS; bk++){ n_ += r[bk * 16 + k]; d_ += r[bk * 16 + 8 + k]; }
        v = n_ / d_;
    }
    out[2097152 + t] = (float)v;
}

__global__ void k_zerond(double* __restrict__ q, int n){
    int i = blockIdx.x * blockDim.x + threadIdx.x;
    if (i < n) q[i] = 0.0;
}

extern "C" void kernel_launch(void* const* d_in, const int* in_sizes, int n_in,
                              void* d_out, int out_size, void* d_ws, size_t ws_size,
                              hipStream_t stream){
    const float* sig = (const float*)d_in[0];
    float* out = (float*)d_out;
    char* p = (char*)d_ws;
    // ws: U 8 MB | FPT 1 MB | D (NDB banks + CNT/flags) ~43 KB  (~9.05 MB total)
    float2* U   = (float2*)p;
    float2* FPT = (float2*)(p + (size_t)8 * 1024 * 1024);
    double* D   = (double*)(p + (size_t)9 * 1024 * 1024);

    // zero NDB D[0..4864) + full CNT/flag span D[4864..5400)
    k_zerond<<<dim3(22), dim3(256), 0, stream>>>(D, 5400);
    k_stageA<<<dim3(16), dim3(1024), 65536, stream>>>(sig, FPT);
    k_vmd_all<<<dim3(VMD_BLOCKS), dim3(512), 0, stream>>>(FPT, U, D);
    k_stageCD<<<dim3(128), dim3(1024), 65536, stream>>>(U);
    k_out0T<<<dim3(32, 8), dim3(256), 0, stream>>>((const float*)U, out);
    k_out1T<<<dim3(128), dim3(256), 0, stream>>>((const float*)U, out);
    k_omega<<<dim3(1), dim3(256), 0, stream>>>(D, out);
}

// Round 16
// 259.006 us; speedup vs baseline: 32.5760x; 1.3584x over previous
//
#include <hip/hip_runtime.h>
#include <math.h>

#define NPAIR 131072          // 8192 freqs x 16 channels
#define STEPS 19
#define VMD_BLOCKS 256        // x 512 threads = NPAIR
#define ND_BANKS 16

// XOR swizzle: spreads strided radix-8 writes across banks; keeps contiguous free
#define SW(a) ((a) ^ (((a) >> 5) & 31))

#define LD_RLX(p)    __hip_atomic_load((p),       __ATOMIC_RELAXED, __HIP_MEMORY_SCOPE_AGENT)
#define ST_RLX(p,v)  __hip_atomic_store((p),(v),  __ATOMIC_RELAXED, __HIP_MEMORY_SCOPE_AGENT)
#define FAA_RLX(p,v) __hip_atomic_fetch_add((p),(v),__ATOMIC_RELAXED, __HIP_MEMORY_SCOPE_AGENT)

__device__ __forceinline__ float2 cadd(float2 a, float2 b){ return make_float2(a.x+b.x, a.y+b.y); }
__device__ __forceinline__ float2 csub(float2 a, float2 b){ return make_float2(a.x-b.x, a.y-b.y); }
__device__ __forceinline__ float2 cmul(float2 a, float2 b){
    return make_float2(a.x*b.x - a.y*b.y, a.x*b.y + a.y*b.x);
}
template<int SGN>
__device__ __forceinline__ float2 imul(float2 a){   // multiply by e^{SGN*i*pi/2}
    return (SGN > 0) ? make_float2(-a.y, a.x) : make_float2(a.y, -a.x);
}

// 8-point DFT: y_k = sum_r a_r e^{SGN*2pi i r k/8}
template<int SGN>
__device__ __forceinline__ void dft8(const float2* a, float2* y){
    const float C = 0.70710678118654752f;
    const float sg = (SGN > 0) ? 1.f : -1.f;
    float2 t0 = cadd(a[0], a[4]), t1 = csub(a[0], a[4]);
    float2 t2 = cadd(a[2], a[6]), t3 = imul<SGN>(csub(a[2], a[6]));
    float2 E0 = cadd(t0, t2), E2 = csub(t0, t2), E1 = cadd(t1, t3), E3 = csub(t1, t3);
    float2 s0 = cadd(a[1], a[5]), s1 = csub(a[1], a[5]);
    float2 s2 = cadd(a[3], a[7]), s3 = imul<SGN>(csub(a[3], a[7]));
    float2 O0 = cadd(s0, s2), O2 = csub(s0, s2), O1 = cadd(s1, s3), O3 = csub(s1, s3);
    float2 w1 = make_float2(C, sg * C), w3 = make_float2(-C, sg * C);
    float2 R0 = O0, R1 = cmul(O1, w1), R2 = imul<SGN>(O2), R3 = cmul(O3, w3);
    y[0] = cadd(E0, R0); y[4] = csub(E0, R0);
    y[1] = cadd(E1, R1); y[5] = csub(E1, R1);
    y[2] = cadd(E2, R2); y[6] = csub(E2, R2);
    y[3] = cadd(E3, R3); y[7] = csub(E3, R3);
}

// ===== in-LDS 8192-pt Stockham FFT: 4 radix-8 passes + 1 radix-2, 1024 threads =====
template<int SGN>
__device__ void lds_fft8192_r8(float2* lds, int tid){
    #pragma unroll
    for (int pi = 0; pi < 4; pi++){
        int ls = 3 * pi;
        int s  = 1 << ls;
        int nn = 8192 >> ls;
        int q = tid & (s - 1);
        float2 a[8], y[8];
        #pragma unroll
        for (int r = 0; r < 8; r++) a[r] = lds[SW(tid + (r << 10))];
        __syncthreads();
        dft8<SGN>(a, y);
        int p = tid >> ls;
        float ang = (float)(2 * p) / (float)nn;
        float sn, cs;
        sincospif(SGN > 0 ? ang : -ang, &sn, &cs);   // w = e^{SGN*2pi i p/nn}
        float2 w = make_float2(cs, sn);
        float2 wk = make_float2(1.f, 0.f);
        int o = q + ((tid - q) << 3);                 // q + 8*s*p
        lds[SW(o)] = y[0];
        #pragma unroll
        for (int k = 1; k < 8; k++){
            wk = cmul(wk, w);
            lds[SW(o + (k << ls))] = cmul(y[k], wk);
        }
        __syncthreads();
    }
    #pragma unroll
    for (int w4 = 0; w4 < 4; w4++){                   // final radix-2, twiddle-free
        int idx = (w4 << 10) + tid;
        float2 a = lds[SW(idx)], b = lds[SW(idx + 4096)];
        lds[SW(idx)]        = cadd(a, b);
        lds[SW(idx + 4096)] = csub(a, b);
    }
    __syncthreads();
}

// ===== stage A: mirror-extend + FFT16384 (split radix via 2x FFT8192) -> FPT =====
__global__ __launch_bounds__(1024) void k_stageA(const float* __restrict__ sig,
                                                 float2* __restrict__ FPT){
    extern __shared__ float2 lds[];
    int tid = threadIdx.x;
    int cw  = blockIdx.x;
    int cs  = (cw + 8) & 15;                 // fftshift over channel axis
    const float* sp = sig + cs * 8192;
    float2 regA[8];
    #pragma unroll
    for (int r = 0; r < 8; r++){             // even samples of mirrored extension
        int p = r * 1024 + tid;
        int x = 2 * p;
        int mx = (x < 4096) ? (4095 - x) : ((x < 12288) ? (x - 4096) : (20479 - x));
        lds[SW(p)] = make_float2(sp[mx], 0.f);
    }
    __syncthreads();
    lds_fft8192_r8<-1>(lds, tid);
    #pragma unroll
    for (int r = 0; r < 8; r++) regA[r] = lds[SW(r * 1024 + tid)];
    __syncthreads();
    #pragma unroll
    for (int r = 0; r < 8; r++){             // odd samples
        int p = r * 1024 + tid;
        int x = 2 * p + 1;
        int mx = (x < 4096) ? (4095 - x) : ((x < 12288) ? (x - 4096) : (20479 - x));
        lds[SW(p)] = make_float2(sp[mx], 0.f);
    }
    __syncthreads();
    lds_fft8192_r8<-1>(lds, tid);
    // combine: F[j] = A[j] + e^{-i pi j/8192} B[j]
    float sn, cn;
    sincospif(-(float)tid / 8192.0f, &sn, &cn);
    float2 w = make_float2(cn, sn);
    const float2 Wst = make_float2(0.92387953251128674f, -0.38268343236508977f); // e^{-i pi/8}
    #pragma unroll
    for (int q = 0; q < 8; q++){
        int j = q * 1024 + tid;
        float2 B = lds[SW(j)];
        float2 t = cmul(B, w);
        FPT[cw * 8192 + j] = make_float2(regA[q].x + t.x, regA[q].y + t.y);
        w = cmul(w, Wst);
    }
}

// ===== fused 19-step VMD: FULLY-RELAXED LLC barrier (no acquire/release anywhere) ====
// Theory (R16): all cross-block data (NDB sums, counters, flags) moves through
// AGENT-scope atomics, which execute at the LLC (bypassing non-coherent per-XCD
// L2). LLC completion order IS the visibility order -> no fences needed. Every
// ACQ_REL/ACQUIRE in R9..R15 emitted L2 writeback/invalidate maintenance (~256
// ops/step) — the suspected ~12 us/step floor, identical across barrier
// topologies AND kernel-relaunch (whose boundaries also flush L2).
// Proven pieces kept: 512-thr blocks (72 VGPR, no spill — R13/14: 1024-thr caps
// VGPR at 64 -> 28-reg spill -> 50 MB scratch); relaxed polls (R11); no O(N)
// serial leader work (R12); banked NDB (R9).
__global__ __launch_bounds__(512, 2) void k_vmd_all(const float2* __restrict__ FPT,
                                                    float2* __restrict__ U,
                                                    double* __restrict__ D){
    double* NDB = D;
    int*    CNT = (int*)(D + 4864);

    int tid = blockIdx.x * 512 + threadIdx.x;   // [0,NPAIR), tid = cw*8192+j
    int j = tid & 8191;
    double fr = (double)j / 16384.0;
    float2 fv = FPT[tid];
    double fx = fv.x, fy = fv.y;
    float urx[8], ury[8];
    double om[8];
    #pragma unroll
    for (int k = 0; k < 8; k++){ urx[k] = 0.f; ury[k] = 0.f; om[k] = 0.0625 * (double)k; }
    __shared__ double lred[8][16];
    __shared__ double ndls[256];
    __shared__ double om_s[8];
    int lane = threadIdx.x & 63, wv = threadIdx.x >> 6;
    int mybank = (blockIdx.x & (ND_BANKS - 1)) * 16;
    int grp = blockIdx.x >> 4;                  // 16 groups of 16 blocks

    for (int step = 0; step < STEPS; step++){
        if (step > 0){
            #pragma unroll
            for (int k = 0; k < 8; k++) om[k] = om_s[k];
        }
        double sx = 0.0, sy = 0.0;
        #pragma unroll
        for (int k = 1; k < 8; k++){ sx += (double)urx[k]; sy += (double)ury[k]; }
        double lx = 0.0, ly = 0.0, nloc[8], dloc[8];
        #pragma unroll
        for (int k = 0; k < 8; k++){
            if (k > 0){ sx += lx - (double)urx[k]; sy += ly - (double)ury[k]; }
            double d = fr - om[k];
            double den = 1.0 + 2000.0 * d * d;
            double nx = (fx - sx) / den, ny = (fy - sy) / den;
            urx[k] = (float)nx; ury[k] = (float)ny;   // replicate complex64 carry
            lx = nx; ly = ny;
            double pw = nx * nx + ny * ny;
            nloc[k] = fr * pw; dloc[k] = pw;
        }
        #pragma unroll
        for (int k = 0; k < 8; k++){
            double a = nloc[k], b = dloc[k];
            for (int off = 32; off > 0; off >>= 1){
                a += __shfl_down(a, off);
                b += __shfl_down(b, off);
            }
            nloc[k] = a; dloc[k] = b;
        }
        if (lane == 0){
            #pragma unroll
            for (int k = 0; k < 8; k++){ lred[wv][k] = nloc[k]; lred[wv][8 + k] = dloc[k]; }
        }
        __syncthreads();
        if (threadIdx.x < 16){
            double sum = 0.0;
            #pragma unroll
            for (int w = 0; w < 8; w++) sum += lred[w][threadIdx.x];
            atomicAdd(&NDB[step * 256 + mybank + threadIdx.x], sum);  // LLC f64 atomic
        }
        __syncthreads();      // wave0 vmcnt drained -> NDB adds COMPLETE at LLC
        if (step < STEPS - 1){
            if (threadIdx.x == 0){
                int target = 16 * (step + 1);   // monotonic counters: no reset race
                int old = FAA_RLX(&CNT[grp * 32], 1);
                if (old == target - 1){         // group-last
                    int rold = FAA_RLX(&CNT[512], 1);
                    if (rold == target - 1){    // root-last: publish release flag
                        ST_RLX(&CNT[544], step + 1);
                    } else {                    // other group-lasts: wait on root flag
                        while (LD_RLX(&CNT[544]) <= step)
                            __builtin_amdgcn_s_sleep(1);
                    }
                    // fan-out: 16 relaxed stores happen IN PARALLEL across group-lasts
                    ST_RLX(&CNT[576 + grp * 32], step + 1);
                } else {                        // members: wait on own group flag
                    while (LD_RLX(&CNT[576 + grp * 32]) <= step)
                        __builtin_amdgcn_s_sleep(1);
                }
            }
            __syncthreads();
            // parallel readback: 256 threads fetch one double each (LLC), sum in LDS
            if (threadIdx.x < 256)
                ndls[threadIdx.x] = LD_RLX(&NDB[step * 256 + threadIdx.x]);
            __syncthreads();
            if (threadIdx.x < 8){
                double n_ = 0.0, d_ = 0.0;
                #pragma unroll
                for (int bk = 0; bk < ND_BANKS; bk++){
                    n_ += ndls[bk * 16 + threadIdx.x];
                    d_ += ndls[bk * 16 + 8 + threadIdx.x];
                }
                om_s[threadIdx.x] = n_ / d_;
            }
            __syncthreads();
        }
    }
    #pragma unroll
    for (int k = 0; k < 8; k++) U[k * NPAIR + tid] = make_float2(urx[k], ury[k]);
}

// ===== stage C+D: hermitian iFFT16384 -> slice -> FFT8192; results into own U slice =====
// After: U32[b*16384 + t] = y[t];  U32[b*16384 + 8192 + t] = Re(Yf[(t+4096) mod 8192])
__global__ __launch_bounds__(1024) void k_stageCD(float2* __restrict__ U){
    extern __shared__ float2 lds[];
    int tid = threadIdx.x;
    int b = blockIdx.x;                      // b = k*16 + cw
    const float2* pos = U + b * 8192;
    float* slice = (float*)(U) + (size_t)b * 16384;
    const float inv = 1.0f / 16384.0f;
    float2 regA[8];
    #pragma unroll
    for (int r = 0; r < 8; r++){             // v_even[p] = v[2p] (hermitian map)
        int p = r * 1024 + tid;
        int m = 2 * p;
        int jj; bool cj;
        if (m == 0)          { jj = 0;         cj = true;  }
        else if (m <= 8191)  { jj = m;         cj = false; }
        else if (m == 8192)  { jj = 8191;      cj = true;  }
        else                 { jj = 16384 - m; cj = true;  }
        float2 pv = pos[jj];
        lds[SW(p)] = make_float2(pv.x, cj ? -pv.y : pv.y);
    }
    __syncthreads();
    lds_fft8192_r8<1>(lds, tid);
    #pragma unroll
    for (int r = 0; r < 8; r++) regA[r] = lds[SW(r * 1024 + tid)];
    __syncthreads();
    #pragma unroll
    for (int r = 0; r < 8; r++){             // v_odd[p] = v[2p+1]
        int p = r * 1024 + tid;
        int m = 2 * p + 1;
        int jj; bool cj;
        if (m <= 8191) { jj = m;         cj = false; }
        else           { jj = 16384 - m; cj = true;  }
        float2 pv = pos[jj];
        lds[SW(p)] = make_float2(pv.x, cj ? -pv.y : pv.y);
    }
    __syncthreads();
    lds_fft8192_r8<1>(lds, tid);
    // combine -> y[t], coalesced write into own slice (all pos reads done)
    float yreg[8];
    float sn, cn;
    sincospif((float)(4096 + tid) / 8192.0f, &sn, &cn);
    float2 w = make_float2(cn, sn);
    const float2 Wst = make_float2(0.92387953251128674f, 0.38268343236508977f);  // e^{+i pi/8}
    #pragma unroll
    for (int q = 0; q < 8; q++){
        int t = q * 1024 + tid;
        int r = (q + 4) & 7;                 // (t+4096) mod 8192 block
        float2 A = regA[r];
        float2 B = lds[SW(r * 1024 + tid)];
        float2 tw = cmul(B, w);
        float yv = (A.x + tw.x) * inv;
        yreg[q] = yv;
        slice[t] = yv;
        w = cmul(w, Wst);
    }
    __syncthreads();
    #pragma unroll
    for (int q = 0; q < 8; q++) lds[SW(q * 1024 + tid)] = make_float2(yreg[q], 0.f);
    __syncthreads();
    lds_fft8192_r8<-1>(lds, tid);            // forward FFT8192 of y
    #pragma unroll
    for (int q = 0; q < 8; q++){
        int t = q * 1024 + tid;
        float2 Y = lds[SW(((q + 4) & 7) * 1024 + tid)];
        slice[8192 + t] = Y.x;               // Re(Yf[(t+4096) mod 8192]), coalesced
    }
}

// ===== transpose 1: out0[(k*8192+t)*16 + ch] = y[k*16+cw][t], ch=(cw+8)&15 =====
__global__ __launch_bounds__(256) void k_out0T(const float* __restrict__ U32,
                                               float* __restrict__ out){
    __shared__ float tile[16][257];
    int tid = threadIdx.x;
    int k  = blockIdx.y;
    int t0 = blockIdx.x * 256;
    #pragma unroll
    for (int cw = 0; cw < 16; cw++)
        tile[cw][tid] = U32[((size_t)(k * 16 + cw)) * 16384 + t0 + tid];
    __syncthreads();
    #pragma unroll
    for (int i = 0; i < 16; i++){
        int flat = i * 256 + tid;            // flat = dt*16 + ch
        int dt = flat >> 4, ch = flat & 15;
        int cw = (ch + 8) & 15;
        out[(size_t)k * 131072 + t0 * 16 + flat] = tile[cw][dt];
    }
}

// ===== transpose 2: out1[1048576 + t*128 + b] = W2[b][t] =====
__global__ __launch_bounds__(256) void k_out1T(const float* __restrict__ U32,
                                               float* __restrict__ out){
    __shared__ float tile[128][65];
    int tid = threadIdx.x;
    int t0 = blockIdx.x * 64;
    #pragma unroll
    for (int i = 0; i < 32; i++){
        int flat = i * 256 + tid;
        int b = flat >> 6, dt = flat & 63;
        tile[b][dt] = U32[(size_t)b * 16384 + 8192 + t0 + dt];
    }
    __syncthreads();
    #pragma unroll
    for (int i = 0; i < 32; i++){
        int flat = i * 256 + tid;
        int dt = flat >> 7, b = flat & 127;
        out[1048576 + (size_t)(t0 + dt) * 128 + b] = tile[b][dt];
    }
}

// ===== omega history: out2 = Re(omega), 160 floats at 2097152 =====
__global__ void k_omega(const double* __restrict__ ndb, float* __restrict__ out){
    int t = threadIdx.x;
    if (t >= 160) return;
    int row = t >> 3, k = t & 7;
    double v;
    if (row == 0){
        v = 0.0625 * (double)k;
    } else {
        const double* r = ndb + (row - 1) * 256;
        double n_ = 0.0, d_ = 0.0;
        #pragma unroll
        for (int bk = 0; bk < ND_BANKS; bk++){ n_ += r[bk * 16 + k]; d_ += r[bk * 16 + 8 + k]; }
        v = n_ / d_;
    }
    out[2097152 + t] = (float)v;
}

__global__ void k_zerond(double* __restrict__ q, int n){
    int i = blockIdx.x * blockDim.x + threadIdx.x;
    if (i < n) q[i] = 0.0;
}

extern "C" void kernel_launch(void* const* d_in, const int* in_sizes, int n_in,
                              void* d_out, int out_size, void* d_ws, size_t ws_size,
                              hipStream_t stream){
    const float* sig = (const float*)d_in[0];
    float* out = (float*)d_out;
    char* p = (char*)d_ws;
    // ws: U 8 MB | FPT 1 MB | D (NDB banks + CNT/flags) ~43 KB  (~9.05 MB total)
    float2* U   = (float2*)p;
    float2* FPT = (float2*)(p + (size_t)8 * 1024 * 1024);
    double* D   = (double*)(p + (size_t)9 * 1024 * 1024);

    // zero NDB D[0..4864) + full CNT/flag span D[4864..5400)
    k_zerond<<<dim3(22), dim3(256), 0, stream>>>(D, 5400);
    k_stageA<<<dim3(16), dim3(1024), 65536, stream>>>(sig, FPT);
    k_vmd_all<<<dim3(VMD_BLOCKS), dim3(512), 0, stream>>>(FPT, U, D);
    k_stageCD<<<dim3(128), dim3(1024), 65536, stream>>>(U);
    k_out0T<<<dim3(32, 8), dim3(256), 0, stream>>>((const float*)U, out);
    k_out1T<<<dim3(128), dim3(256), 0, stream>>>((const float*)U, out);
    k_omega<<<dim3(1), dim3(256), 0, stream>>>(D, out);
}